// Round 5
// baseline (570.943 us; speedup 1.0000x reference)
//
#include <hip/hip_runtime.h>
#include <hip/hip_bf16.h>

#define F 128
#define C_CLS 40
#define NWSPLIT 35
#define ELLCAP 32
#define NBKT 9

typedef __attribute__((ext_vector_type(8))) short short8;
typedef __attribute__((ext_vector_type(4))) float float4v;
typedef unsigned short ushort;

__device__ inline float bf2f(ushort u) {
  unsigned int x = ((unsigned int)u) << 16;
  return __builtin_bit_cast(float, x);
}
__device__ inline ushort f2bf(float f) {
  __hip_bfloat16 h = __float2bfloat16(f);
  return __builtin_bit_cast(ushort, h);
}
__device__ inline void split_bf16(float f, ushort& hi, ushort& lo) {
  hi = f2bf(f);
  lo = f2bf(f - bf2f(hi));
}
__device__ inline int swz(int lane) { return lane ^ ((lane >> 4) & 3); }
// bucket: descending by iteration count (long waves launch first)
__device__ inline int bucket_of(int cv) {
  int lim = cv < ELLCAP ? cv : ELLCAP;
  int nIt = (lim + 3) >> 2;           // 0..8
  return 8 - nIt;                     // 0 = deg 29..32
}

// ---------------- setup (heterogeneous): weight-split | ELL fill ----------------
__global__ __launch_bounds__(256) void setup_kernel(
    const float* __restrict__ W1, const float* __restrict__ imp,
    const float* __restrict__ W2, const float* __restrict__ W3,
    const float* __restrict__ Wl1, const float* __restrict__ Wh2,
    ushort* __restrict__ WhP,
    ushort* __restrict__ W2hH, ushort* __restrict__ W2lH,
    const int* __restrict__ row, const int* __restrict__ col,
    int* __restrict__ cnt, int* __restrict__ ell,
    int ne, int n) {
  int b = blockIdx.x;
  if (b < NWSPLIT) {
    int ci = b * 256 + threadIdx.x;
    if (ci < 8192) {
      const float* src[4] = {W1, W2, W3, Wl1};
      int p = ci >> 11, c = ci & 2047;
      int kc = c >> 10, ct = (c >> 7) & 7, ks = (c >> 6) & 1, ln = c & 63;
      int dl = swz(ln);
      int colw = ct * 16 + (dl & 15);
      int k = kc * 64 + ks * 32 + (dl >> 4) * 8;
      float4 f0 = *(const float4*)&src[p][(size_t)colw * F + k];
      float4 f1 = *(const float4*)&src[p][(size_t)colw * F + k + 4];
      float v[8] = {f0.x, f0.y, f0.z, f0.w, f1.x, f1.y, f1.z, f1.w};
      if (p == 0) {
        float4 i0 = *(const float4*)&imp[k];
        float4 i1 = *(const float4*)&imp[k + 4];
        v[0] *= i0.x; v[1] *= i0.y; v[2] *= i0.z; v[3] *= i0.w;
        v[4] *= i1.x; v[5] *= i1.y; v[6] *= i1.z; v[7] *= i1.w;
      }
      ushort hi[8];
#pragma unroll
      for (int j = 0; j < 8; ++j) hi[j] = f2bf(v[j]);
      *(short8*)&WhP[(size_t)ci * 8] = *(short8*)hi;
    } else if (ci < 8192 + 768) {
      int c = ci - 8192;
      int ct = c >> 8, ks = (c >> 6) & 3, ln = c & 63;
      int colw = ct * 16 + (ln & 15);
      int k = ks * 32 + (ln >> 4) * 8;
      float v[8];
      if (colw < C_CLS) {
        float4 f0 = *(const float4*)&Wh2[(size_t)colw * F + k];
        float4 f1 = *(const float4*)&Wh2[(size_t)colw * F + k + 4];
        v[0] = f0.x; v[1] = f0.y; v[2] = f0.z; v[3] = f0.w;
        v[4] = f1.x; v[5] = f1.y; v[6] = f1.z; v[7] = f1.w;
      } else {
#pragma unroll
        for (int j = 0; j < 8; ++j) v[j] = 0.f;
      }
      ushort hi[8], lo[8];
#pragma unroll
      for (int j = 0; j < 8; ++j) split_bf16(v[j], hi[j], lo[j]);
      *(short8*)&W2hH[(size_t)c * 8] = *(short8*)hi;
      *(short8*)&W2lH[(size_t)c * 8] = *(short8*)lo;
    }
  } else {
    int e = (b - NWSPLIT) * 256 + threadIdx.x;
    if (e < ne) {
      int r = row[e], c = col[e];
      int p = atomicAdd(&cnt[c], 1);
      if (p < ELLCAP) ell[(size_t)c * ELLCAP + p] = r;
    }
  }
}

// ---------------- prepass1: wsum + ELL tail rewrite + bucket hist | x -> Xs | zero rows ----
__global__ __launch_bounds__(256) void prepass_kernel(
    const float* __restrict__ x, const int* __restrict__ cnt,
    int* __restrict__ ell, float* __restrict__ wsum, int* __restrict__ hist,
    ushort* __restrict__ Xs, ushort* __restrict__ Az,
    int n, int nbW, int nbX) {
  int b = blockIdx.x;
  if (b < nbW) {
    __shared__ int lh[NBKT];
    int t = threadIdx.x;
    if (t < NBKT) lh[t] = 0;
    __syncthreads();
    int node = b * 256 + t;
    if (node < n) {
      int cv = cnt[node];
      int lim = cv < ELLCAP ? cv : ELLCAP;
      int lim4 = (lim + 3) & ~3;
      float gs = 0.f;
      const int4* ep = (const int4*)&ell[(size_t)node * ELLCAP];
      for (int base = 0; base < lim; base += 4) {
        int4 rr = ep[base >> 2];
        bool p1 = base + 1 < lim, p2 = base + 2 < lim, p3 = base + 3 < lim;
        int r1 = p1 ? rr.y : rr.x;
        int r2 = p2 ? rr.z : rr.x;
        int r3 = p3 ? rr.w : rr.x;
        float g0 = rsqrtf((float)(cnt[rr.x] + 1));
        float g1 = p1 ? rsqrtf((float)(cnt[r1] + 1)) : 0.f;
        float g2 = p2 ? rsqrtf((float)(cnt[r2] + 1)) : 0.f;
        float g3 = p3 ? rsqrtf((float)(cnt[r3] + 1)) : 0.f;
        gs += (g0 + g1) + (g2 + g3);
      }
      float d = (float)(cv + 1);
      wsum[node] = rsqrtf(d) * gs + 1.0f / d;
      for (int p = lim; p < lim4; ++p) ell[(size_t)node * ELLCAP + p] = n;
      atomicAdd(&lh[bucket_of(cv)], 1);
    }
    __syncthreads();
    if (t < NBKT) atomicAdd(&hist[t], lh[t]);
  } else if (b < nbW + nbX) {
    size_t i = (size_t)(b - nbW) * 2048 + (size_t)threadIdx.x * 8;
    if (i < (size_t)n * F) {
      int node = (int)(i >> 7);
      float dc = rsqrtf((float)(cnt[node] + 1));
      float4 f0 = *(const float4*)&x[i];
      float4 f1 = *(const float4*)&x[i + 4];
      ushort o[8] = {f2bf(dc * f0.x), f2bf(dc * f0.y), f2bf(dc * f0.z), f2bf(dc * f0.w),
                     f2bf(dc * f1.x), f2bf(dc * f1.y), f2bf(dc * f1.z), f2bf(dc * f1.w)};
      *(short8*)&Xs[i] = *(short8*)o;
    }
  } else {
    int t = threadIdx.x;
    short8 z = (short8){0, 0, 0, 0, 0, 0, 0, 0};
    if (t < 16) *(short8*)&Xs[(size_t)n * F + t * 8] = z;
    else if (t < 32) *(short8*)&Az[(size_t)n * F + (t - 16) * 8] = z;
  }
}

// ---------------- prepass2: degree-bucket counting-sort scatter -> perm ----------------
__global__ __launch_bounds__(256) void perm_kernel(
    const int* __restrict__ cnt, const int* __restrict__ hist,
    int* __restrict__ cursor, int* __restrict__ perm, int n) {
  __shared__ int lh[NBKT], lbase[NBKT];
  int t = threadIdx.x;
  if (t < NBKT) lh[t] = 0;
  __syncthreads();
  int node = blockIdx.x * 256 + t;
  int bkt = 0, idx = 0;
  if (node < n) {
    bkt = bucket_of(cnt[node]);
    idx = atomicAdd(&lh[bkt], 1);
  }
  __syncthreads();
  if (t < NBKT) {
    int pre = 0;
#pragma unroll
    for (int k = 0; k < NBKT; ++k)
      if (k < t) pre += hist[k];
    lbase[t] = pre + atomicAdd(&cursor[t], lh[t]);
  }
  __syncthreads();
  if (node < n) perm[lbase[bkt] + idx] = node;
}

// ---------------- conv layers 1-2: PERSISTENT degree-uniform gather + MFMA ----------------
// 1280 blocks (5/CU, pinned by launch_bounds(256,5)), grid-stride over node groups.
// S = dc*(sum_nbr Xs[r] + Xs[node]); out = dc*relu((S@W^T + wsum*bl)*invdeg + bc).
__global__ __launch_bounds__(256, 5) void conv_fused(
    const int* __restrict__ cnt, const int* __restrict__ ell,
    const int* __restrict__ perm,
    const ushort* __restrict__ Xs, const ushort* __restrict__ Wh,
    const float* __restrict__ wsum, const float* __restrict__ bl,
    const float* __restrict__ bc, ushort* __restrict__ OUT, int n) {
  const int t = threadIdx.x;
  const int w = t >> 6, lane = t & 63, quad = lane >> 4, cl = lane & 15;
  const int sl = swz(lane);
  const int qoff = quad * 8;

  for (int gbase = blockIdx.x * 64; gbase < n; gbase += gridDim.x * 64) {
    const int gid = gbase + w * 16 + cl;
    const bool valid = gid < n;
    const int node = valid ? perm[gid] : 0;

    float acc[4][8];
#pragma unroll
    for (int ks = 0; ks < 4; ++ks)
#pragma unroll
      for (int q = 0; q < 8; ++q) acc[ks][q] = 0.f;

    float dc = 1.f, id = 1.f;
    int nIt = 0;
    if (valid) {
      int cv = cnt[node];
      float d = (float)(cv + 1);
      dc = rsqrtf(d);
      id = 1.0f / d;
      int lim = cv < ELLCAP ? cv : ELLCAP;
      nIt = (lim + 3) >> 2;
    }
    const int4* ep = (const int4*)&ell[(size_t)node * ELLCAP];

    if (nIt > 0) {
      int4 rr = ep[0];
      for (int it = 0; it < nIt; ++it) {
        const ushort* r0 = &Xs[(size_t)rr.x * F + qoff];
        const ushort* r1 = &Xs[(size_t)rr.y * F + qoff];
        const ushort* r2 = &Xs[(size_t)rr.z * F + qoff];
        const ushort* r3 = &Xs[(size_t)rr.w * F + qoff];
        short8 v[4][4];
#pragma unroll
        for (int ks = 0; ks < 4; ++ks) {
          v[0][ks] = *(const short8*)&r0[ks * 32];
          v[1][ks] = *(const short8*)&r1[ks * 32];
          v[2][ks] = *(const short8*)&r2[ks * 32];
          v[3][ks] = *(const short8*)&r3[ks * 32];
        }
        int jn = (it + 1 < nIt) ? it + 1 : it;
        rr = ep[jn];  // prefetch next indices while rows are in flight
#pragma unroll
        for (int ks = 0; ks < 4; ++ks)
#pragma unroll
          for (int q = 0; q < 8; ++q) {
            float t0 = bf2f((ushort)v[0][ks][q]) + bf2f((ushort)v[1][ks][q]);
            float t1 = bf2f((ushort)v[2][ks][q]) + bf2f((ushort)v[3][ks][q]);
            acc[ks][q] += t0 + t1;
          }
      }
    }

    short8 sfrag[4];
    if (valid) {
      const ushort* sq = &Xs[(size_t)node * F + qoff];
#pragma unroll
      for (int ks = 0; ks < 4; ++ks) {
        short8 sv = *(const short8*)&sq[ks * 32];
        ushort o[8];
#pragma unroll
        for (int q = 0; q < 8; ++q)
          o[q] = f2bf(dc * (acc[ks][q] + bf2f((ushort)sv[q])));
        sfrag[ks] = *(short8*)o;
      }
    } else {
#pragma unroll
      for (int ks = 0; ks < 4; ++ks) sfrag[ks] = (short8){0, 0, 0, 0, 0, 0, 0, 0};
    }

    float4v co[8];
#pragma unroll
    for (int mt = 0; mt < 8; ++mt) co[mt] = (float4v){0.f, 0.f, 0.f, 0.f};
#pragma unroll
    for (int ks = 0; ks < 4; ++ks) {
      const int base2 = ((ks >> 1) * 1024 + (ks & 1) * 64 + sl) * 8;
#pragma unroll
      for (int mt = 0; mt < 8; ++mt) {
        short8 a_h = *(const short8*)&Wh[base2 + mt * 1024];
        co[mt] = __builtin_amdgcn_mfma_f32_16x16x32_bf16(a_h, sfrag[ks], co[mt], 0, 0, 0);
      }
    }

    if (valid) {
      float ws = wsum[node];
#pragma unroll
      for (int mt = 0; mt < 8; ++mt) {
        float4 blv = *(const float4*)&bl[mt * 16 + quad * 4];
        float4 bcv = *(const float4*)&bc[mt * 16 + quad * 4];
        float v0 = fmaxf((co[mt][0] + ws * blv.x) * id + bcv.x, 0.f) * dc;
        float v1 = fmaxf((co[mt][1] + ws * blv.y) * id + bcv.y, 0.f) * dc;
        float v2 = fmaxf((co[mt][2] + ws * blv.z) * id + bcv.z, 0.f) * dc;
        float v3 = fmaxf((co[mt][3] + ws * blv.w) * id + bcv.w, 0.f) * dc;
        ushort o[4] = {f2bf(v0), f2bf(v1), f2bf(v2), f2bf(v3)};
        *(ushort4*)&OUT[(size_t)node * F + mt * 16 + quad * 4] = *(ushort4*)o;
      }
    }
  }
}

// ---------------- conv3 + dense head + log_softmax, fully fused, zero barriers ----------------
// Gather+MFMA(W3)+epilogue as above (unscaled). Then per-wave LDS exchange (C-layout ->
// B-fragment, head_fused's proven swizzle), lin1 MFMA, second exchange, lin2 (hi+lo) +
// log-softmax. All LDS traffic is wave-private; out rows routed via __shfl over perm.
__global__ __launch_bounds__(256) void conv_head(
    const int* __restrict__ cnt, const int* __restrict__ ell,
    const int* __restrict__ perm,
    const ushort* __restrict__ Xs, const ushort* __restrict__ Wh3,
    const float* __restrict__ wsum, const float* __restrict__ bl3,
    const float* __restrict__ bc3,
    const ushort* __restrict__ Wl1h, const float* __restrict__ bli1,
    const ushort* __restrict__ W2h, const ushort* __restrict__ W2l,
    const float* __restrict__ b2, float* __restrict__ out, int n) {
  __shared__ ushort sH[8192];  // 16 KB: 4 waves x 16 rows x 128 bf16 (per-wave private)
  const int t = threadIdx.x;
  const int w = t >> 6, lane = t & 63, quad = lane >> 4, cl = lane & 15;
  const int sl = swz(lane);
  const int qoff = quad * 8;
  char* sHb = (char*)sH;

  const int gid = blockIdx.x * 64 + w * 16 + cl;
  const bool valid = gid < n;
  const int node = valid ? perm[gid] : 0;

  // ---- gather ----
  float acc[4][8];
#pragma unroll
  for (int ks = 0; ks < 4; ++ks)
#pragma unroll
    for (int q = 0; q < 8; ++q) acc[ks][q] = 0.f;

  float dc = 1.f, id = 1.f, ws = 0.f;
  int nIt = 0;
  if (valid) {
    int cv = cnt[node];
    float d = (float)(cv + 1);
    dc = rsqrtf(d);
    id = 1.0f / d;
    ws = wsum[node];
    int lim = cv < ELLCAP ? cv : ELLCAP;
    nIt = (lim + 3) >> 2;
  }
  const int4* ep = (const int4*)&ell[(size_t)node * ELLCAP];

  if (nIt > 0) {
    int4 rr = ep[0];
    for (int it = 0; it < nIt; ++it) {
      const ushort* r0 = &Xs[(size_t)rr.x * F + qoff];
      const ushort* r1 = &Xs[(size_t)rr.y * F + qoff];
      const ushort* r2 = &Xs[(size_t)rr.z * F + qoff];
      const ushort* r3 = &Xs[(size_t)rr.w * F + qoff];
      short8 v[4][4];
#pragma unroll
      for (int ks = 0; ks < 4; ++ks) {
        v[0][ks] = *(const short8*)&r0[ks * 32];
        v[1][ks] = *(const short8*)&r1[ks * 32];
        v[2][ks] = *(const short8*)&r2[ks * 32];
        v[3][ks] = *(const short8*)&r3[ks * 32];
      }
      int jn = (it + 1 < nIt) ? it + 1 : it;
      rr = ep[jn];
#pragma unroll
      for (int ks = 0; ks < 4; ++ks)
#pragma unroll
        for (int q = 0; q < 8; ++q) {
          float t0 = bf2f((ushort)v[0][ks][q]) + bf2f((ushort)v[1][ks][q]);
          float t1 = bf2f((ushort)v[2][ks][q]) + bf2f((ushort)v[3][ks][q]);
          acc[ks][q] += t0 + t1;
        }
    }
  }

  short8 sfrag[4];
  if (valid) {
    const ushort* sq = &Xs[(size_t)node * F + qoff];
#pragma unroll
    for (int ks = 0; ks < 4; ++ks) {
      short8 sv = *(const short8*)&sq[ks * 32];
      ushort o[8];
#pragma unroll
      for (int q = 0; q < 8; ++q)
        o[q] = f2bf(dc * (acc[ks][q] + bf2f((ushort)sv[q])));
      sfrag[ks] = *(short8*)o;
    }
  } else {
#pragma unroll
    for (int ks = 0; ks < 4; ++ks) sfrag[ks] = (short8){0, 0, 0, 0, 0, 0, 0, 0};
  }

  // ---- conv3 MFMA ----
  float4v co[8];
#pragma unroll
  for (int mt = 0; mt < 8; ++mt) co[mt] = (float4v){0.f, 0.f, 0.f, 0.f};
#pragma unroll
  for (int ks = 0; ks < 4; ++ks) {
    const int base2 = ((ks >> 1) * 1024 + (ks & 1) * 64 + sl) * 8;
#pragma unroll
    for (int mt = 0; mt < 8; ++mt) {
      short8 a_h = *(const short8*)&Wh3[base2 + mt * 1024];
      co[mt] = __builtin_amdgcn_mfma_f32_16x16x32_bf16(a_h, sfrag[ks], co[mt], 0, 0, 0);
    }
  }

  // ---- exchange 1: conv3 epilogue -> LDS (A rows, bf16, swizzled) ----
#pragma unroll
  for (int mt = 0; mt < 8; ++mt) {
    float4 blv = *(const float4*)&bl3[mt * 16 + quad * 4];
    float4 bcv = *(const float4*)&bc3[mt * 16 + quad * 4];
    ushort o[4];
    o[0] = f2bf(fmaxf((co[mt][0] + ws * blv.x) * id + bcv.x, 0.f));
    o[1] = f2bf(fmaxf((co[mt][1] + ws * blv.y) * id + bcv.y, 0.f));
    o[2] = f2bf(fmaxf((co[mt][2] + ws * blv.z) * id + bcv.z, 0.f));
    o[3] = f2bf(fmaxf((co[mt][3] + ws * blv.w) * id + bcv.w, 0.f));
    int ch = (mt * 2 + (quad >> 1)) ^ cl;
    *(ushort4*)&sHb[w * 4096 + cl * 256 + ch * 16 + (quad & 1) * 8] = *(ushort4*)o;
  }

  // ---- lin1: h = relu(A @ Wl1^T + bli1) ----
  float4v acc1[8];
#pragma unroll
  for (int mt = 0; mt < 8; ++mt) acc1[mt] = (float4v){0.f, 0.f, 0.f, 0.f};
#pragma unroll
  for (int ks = 0; ks < 4; ++ks) {
    int ch2 = (ks * 4 + quad) ^ cl;
    short8 bfr = *(short8*)&sHb[w * 4096 + cl * 256 + ch2 * 16];
    const int base2 = ((ks >> 1) * 1024 + (ks & 1) * 64 + sl) * 8;
#pragma unroll
    for (int mt = 0; mt < 8; ++mt) {
      short8 a_h = *(const short8*)&Wl1h[base2 + mt * 1024];
      acc1[mt] = __builtin_amdgcn_mfma_f32_16x16x32_bf16(a_h, bfr, acc1[mt], 0, 0, 0);
    }
  }

  // ---- exchange 2: h -> LDS (same swizzle, same region) ----
#pragma unroll
  for (int mt = 0; mt < 8; ++mt) {
    float4 bv = *(const float4*)&bli1[mt * 16 + quad * 4];
    ushort o[4];
    o[0] = f2bf(fmaxf(acc1[mt][0] + bv.x, 0.f));
    o[1] = f2bf(fmaxf(acc1[mt][1] + bv.y, 0.f));
    o[2] = f2bf(fmaxf(acc1[mt][2] + bv.z, 0.f));
    o[3] = f2bf(fmaxf(acc1[mt][3] + bv.w, 0.f));
    int ch = (mt * 2 + (quad >> 1)) ^ cl;
    *(ushort4*)&sHb[w * 4096 + cl * 256 + ch * 16 + (quad & 1) * 8] = *(ushort4*)o;
  }

  // ---- lin2 (hi+lo) + log_softmax ----
  float4v accl[3];
#pragma unroll
  for (int ct = 0; ct < 3; ++ct) accl[ct] = (float4v){0.f, 0.f, 0.f, 0.f};
#pragma unroll
  for (int ks = 0; ks < 4; ++ks) {
    int ch2 = (ks * 4 + quad) ^ cl;
    short8 a = *(short8*)&sHb[w * 4096 + cl * 256 + ch2 * 16];
#pragma unroll
    for (int ct = 0; ct < 3; ++ct) {
      int chunk = ((ct * 4 + ks) * 64 + lane) * 8;
      short8 b_h = *(const short8*)&W2h[chunk];
      short8 b_l = *(const short8*)&W2l[chunk];
      accl[ct] = __builtin_amdgcn_mfma_f32_16x16x32_bf16(a, b_h, accl[ct], 0, 0, 0);
      accl[ct] = __builtin_amdgcn_mfma_f32_16x16x32_bf16(a, b_l, accl[ct], 0, 0, 0);
    }
  }

  float b0 = b2[cl];
  float b1 = b2[16 + cl];
  float b2v = (32 + cl < C_CLS) ? b2[32 + cl] : -1e30f;
  float lse[4];
#pragma unroll
  for (int reg = 0; reg < 4; ++reg) {
    float v0 = accl[0][reg] + b0;
    float v1 = accl[1][reg] + b1;
    float v2 = accl[2][reg] + b2v;
    accl[0][reg] = v0; accl[1][reg] = v1; accl[2][reg] = v2;
    float m = fmaxf(fmaxf(v0, v1), v2);
#pragma unroll
    for (int o = 1; o < 16; o <<= 1) m = fmaxf(m, __shfl_xor(m, o));
    float s = __expf(v0 - m) + __expf(v1 - m) + __expf(v2 - m);
#pragma unroll
    for (int o = 1; o < 16; o <<= 1) s += __shfl_xor(s, o);
    lse[reg] = logf(s) + m;
  }
  int vn = valid ? node : -1;
#pragma unroll
  for (int reg = 0; reg < 4; ++reg) {
    int s = quad * 4 + reg;          // node slot within the wave's 16-row tile
    int gn = __shfl(vn, s);
    if (gn >= 0) {
      out[(size_t)gn * C_CLS + cl] = accl[0][reg] - lse[reg];
      out[(size_t)gn * C_CLS + 16 + cl] = accl[1][reg] - lse[reg];
      if (cl < 8) out[(size_t)gn * C_CLS + 32 + cl] = accl[2][reg] - lse[reg];
    }
  }
}

extern "C" void kernel_launch(void* const* d_in, const int* in_sizes, int n_in,
                              void* d_out, int out_size, void* d_ws, size_t ws_size,
                              hipStream_t stream) {
  const float* x    = (const float*)d_in[0];
  const int*   ei   = (const int*)d_in[1];
  const float* imp  = (const float*)d_in[2];
  const float* W1   = (const float*)d_in[3];
  const float* bl1  = (const float*)d_in[4];
  const float* bc1  = (const float*)d_in[5];
  const float* W2   = (const float*)d_in[6];
  const float* bl2  = (const float*)d_in[7];
  const float* bc2  = (const float*)d_in[8];
  const float* W3   = (const float*)d_in[9];
  const float* bl3  = (const float*)d_in[10];
  const float* bc3  = (const float*)d_in[11];
  const float* Wl1  = (const float*)d_in[12];
  const float* bli1 = (const float*)d_in[13];
  const float* Wl2  = (const float*)d_in[14];
  const float* bli2 = (const float*)d_in[15];
  float* out = (float*)d_out;

  const int N = in_sizes[0] / F;      // 100000
  const int E = in_sizes[1] / 2;      // 600000

  // ping-pong buffers have N+1 rows; row N is the shared zero row for ELL tails
  ushort* A16 = (ushort*)d_ws;                     // (N+1)*F
  ushort* B16 = A16 + (size_t)(N + 1) * F;         // (N+1)*F
  ushort* WhP = B16 + (size_t)(N + 1) * F;         // 8192*8
  ushort* W2hH = WhP + 65536;                      // 768*8
  ushort* W2lH = W2hH + 6144;                      // 768*8
  float* wsum = (float*)(W2lH + 6144);             // N
  int*   cnt  = (int*)(wsum + N);                  // N (packed)
  int*   hist = cnt + N;                           // 9
  int*   cursor = hist + NBKT;                     // 9
  int*   perm = cursor + NBKT;                     // N
  int*   ell  = perm + N;                          // 32N

  const int* rowv = ei;
  const int* colv = ei + E;

  int nbE  = (E + 255) / 256;
  int nbW  = (N + 255) / 256;          // prepass wsum/hist blocks
  int nbX  = (N * F + 2047) / 2048;    // prepass x->Xs blocks (8 elems/thread)
  int nbCv = (N + 63) / 64;            // node groups (64 nodes each)
  int nbP  = nbCv < 1280 ? nbCv : 1280;  // persistent conv grid: 5 blocks/CU

  // ---- one-time prep ----
  hipMemsetAsync(cnt, 0, ((size_t)N + 2 * NBKT) * sizeof(int), stream);
  setup_kernel<<<NWSPLIT + nbE, 256, 0, stream>>>(
      W1, imp, W2, W3, Wl1, Wl2, WhP, W2hH, W2lH, rowv, colv, cnt, ell, E, N);
  prepass_kernel<<<nbW + nbX + 1, 256, 0, stream>>>(
      x, cnt, ell, wsum, hist, B16, A16, N, nbW, nbX);
  perm_kernel<<<nbW, 256, 0, stream>>>(cnt, hist, cursor, perm, N);

  // ---- conv layers 1-2: persistent, residency-pinned ----
  conv_fused<<<nbP, 256, 0, stream>>>(cnt, ell, perm, B16, WhP,         wsum, bl1, bc1, A16, N);
  conv_fused<<<nbP, 256, 0, stream>>>(cnt, ell, perm, A16, WhP + 16384, wsum, bl2, bc2, B16, N);

  // ---- conv layer 3 + dense head + log_softmax, fully fused ----
  conv_head<<<nbCv, 256, 0, stream>>>(cnt, ell, perm, B16, WhP + 32768, wsum, bl3, bc3,
                                      WhP + 49152, bli1, W2hH, W2lH, bli2, out, N);
}

// Round 6
// 351.157 us; speedup vs baseline: 1.6259x; 1.6259x over previous
//
#include <hip/hip_runtime.h>
#include <hip/hip_bf16.h>

#define F 128
#define C_CLS 40
#define NWSPLIT 35
#define ELLCAP 32
#define NBKT 9

typedef __attribute__((ext_vector_type(8))) short short8;
typedef __attribute__((ext_vector_type(4))) float float4v;
typedef unsigned short ushort;

__device__ inline float bf2f(ushort u) {
  unsigned int x = ((unsigned int)u) << 16;
  return __builtin_bit_cast(float, x);
}
__device__ inline ushort f2bf(float f) {
  __hip_bfloat16 h = __float2bfloat16(f);
  return __builtin_bit_cast(ushort, h);
}
__device__ inline void split_bf16(float f, ushort& hi, ushort& lo) {
  hi = f2bf(f);
  lo = f2bf(f - bf2f(hi));
}
__device__ inline int swz(int lane) { return lane ^ ((lane >> 4) & 3); }
// bucket: descending by iteration count (long waves launch first)
__device__ inline int bucket_of(int cv) {
  int lim = cv < ELLCAP ? cv : ELLCAP;
  int nIt = (lim + 3) >> 2;           // 0..8
  return 8 - nIt;                     // 0 = deg 29..32
}

// ---------------- setup (heterogeneous): weight-split | ELL fill ----------------
__global__ __launch_bounds__(256) void setup_kernel(
    const float* __restrict__ W1, const float* __restrict__ imp,
    const float* __restrict__ W2, const float* __restrict__ W3,
    const float* __restrict__ Wl1, const float* __restrict__ Wh2,
    ushort* __restrict__ WhP,
    ushort* __restrict__ W2hH, ushort* __restrict__ W2lH,
    const int* __restrict__ row, const int* __restrict__ col,
    int* __restrict__ cnt, int* __restrict__ ell,
    int ne, int n) {
  int b = blockIdx.x;
  if (b < NWSPLIT) {
    int ci = b * 256 + threadIdx.x;
    if (ci < 8192) {
      const float* src[4] = {W1, W2, W3, Wl1};
      int p = ci >> 11, c = ci & 2047;
      int kc = c >> 10, ct = (c >> 7) & 7, ks = (c >> 6) & 1, ln = c & 63;
      int dl = swz(ln);
      int colw = ct * 16 + (dl & 15);
      int k = kc * 64 + ks * 32 + (dl >> 4) * 8;
      float4 f0 = *(const float4*)&src[p][(size_t)colw * F + k];
      float4 f1 = *(const float4*)&src[p][(size_t)colw * F + k + 4];
      float v[8] = {f0.x, f0.y, f0.z, f0.w, f1.x, f1.y, f1.z, f1.w};
      if (p == 0) {
        float4 i0 = *(const float4*)&imp[k];
        float4 i1 = *(const float4*)&imp[k + 4];
        v[0] *= i0.x; v[1] *= i0.y; v[2] *= i0.z; v[3] *= i0.w;
        v[4] *= i1.x; v[5] *= i1.y; v[6] *= i1.z; v[7] *= i1.w;
      }
      ushort hi[8];
#pragma unroll
      for (int j = 0; j < 8; ++j) hi[j] = f2bf(v[j]);
      *(short8*)&WhP[(size_t)ci * 8] = *(short8*)hi;
    } else if (ci < 8192 + 768) {
      int c = ci - 8192;
      int ct = c >> 8, ks = (c >> 6) & 3, ln = c & 63;
      int colw = ct * 16 + (ln & 15);
      int k = ks * 32 + (ln >> 4) * 8;
      float v[8];
      if (colw < C_CLS) {
        float4 f0 = *(const float4*)&Wh2[(size_t)colw * F + k];
        float4 f1 = *(const float4*)&Wh2[(size_t)colw * F + k + 4];
        v[0] = f0.x; v[1] = f0.y; v[2] = f0.z; v[3] = f0.w;
        v[4] = f1.x; v[5] = f1.y; v[6] = f1.z; v[7] = f1.w;
      } else {
#pragma unroll
        for (int j = 0; j < 8; ++j) v[j] = 0.f;
      }
      ushort hi[8], lo[8];
#pragma unroll
      for (int j = 0; j < 8; ++j) split_bf16(v[j], hi[j], lo[j]);
      *(short8*)&W2hH[(size_t)c * 8] = *(short8*)hi;
      *(short8*)&W2lH[(size_t)c * 8] = *(short8*)lo;
    }
  } else {
    int e = (b - NWSPLIT) * 256 + threadIdx.x;
    if (e < ne) {
      int r = row[e], c = col[e];
      int p = atomicAdd(&cnt[c], 1);
      if (p < ELLCAP) ell[(size_t)c * ELLCAP + p] = r;
    }
  }
}

// ---------------- prepass1: wsum + ELL tail rewrite + bucket hist | x -> Xs | zero rows ----
__global__ __launch_bounds__(256) void prepass_kernel(
    const float* __restrict__ x, const int* __restrict__ cnt,
    int* __restrict__ ell, float* __restrict__ wsum, int* __restrict__ hist,
    ushort* __restrict__ Xs, ushort* __restrict__ Az,
    int n, int nbW, int nbX) {
  int b = blockIdx.x;
  if (b < nbW) {
    __shared__ int lh[NBKT];
    int t = threadIdx.x;
    if (t < NBKT) lh[t] = 0;
    __syncthreads();
    int node = b * 256 + t;
    if (node < n) {
      int cv = cnt[node];
      int lim = cv < ELLCAP ? cv : ELLCAP;
      int lim4 = (lim + 3) & ~3;
      float gs = 0.f;
      const int4* ep = (const int4*)&ell[(size_t)node * ELLCAP];
      for (int base = 0; base < lim; base += 4) {
        int4 rr = ep[base >> 2];
        bool p1 = base + 1 < lim, p2 = base + 2 < lim, p3 = base + 3 < lim;
        int r1 = p1 ? rr.y : rr.x;
        int r2 = p2 ? rr.z : rr.x;
        int r3 = p3 ? rr.w : rr.x;
        float g0 = rsqrtf((float)(cnt[rr.x] + 1));
        float g1 = p1 ? rsqrtf((float)(cnt[r1] + 1)) : 0.f;
        float g2 = p2 ? rsqrtf((float)(cnt[r2] + 1)) : 0.f;
        float g3 = p3 ? rsqrtf((float)(cnt[r3] + 1)) : 0.f;
        gs += (g0 + g1) + (g2 + g3);
      }
      float d = (float)(cv + 1);
      wsum[node] = rsqrtf(d) * gs + 1.0f / d;
      for (int p = lim; p < lim4; ++p) ell[(size_t)node * ELLCAP + p] = n;
      atomicAdd(&lh[bucket_of(cv)], 1);
    }
    __syncthreads();
    if (t < NBKT) atomicAdd(&hist[t], lh[t]);
  } else if (b < nbW + nbX) {
    size_t i = (size_t)(b - nbW) * 2048 + (size_t)threadIdx.x * 8;
    if (i < (size_t)n * F) {
      int node = (int)(i >> 7);
      float dc = rsqrtf((float)(cnt[node] + 1));
      float4 f0 = *(const float4*)&x[i];
      float4 f1 = *(const float4*)&x[i + 4];
      ushort o[8] = {f2bf(dc * f0.x), f2bf(dc * f0.y), f2bf(dc * f0.z), f2bf(dc * f0.w),
                     f2bf(dc * f1.x), f2bf(dc * f1.y), f2bf(dc * f1.z), f2bf(dc * f1.w)};
      *(short8*)&Xs[i] = *(short8*)o;
    }
  } else {
    int t = threadIdx.x;
    short8 z = (short8){0, 0, 0, 0, 0, 0, 0, 0};
    if (t < 16) *(short8*)&Xs[(size_t)n * F + t * 8] = z;
    else if (t < 32) *(short8*)&Az[(size_t)n * F + (t - 16) * 8] = z;
  }
}

// ---------------- prepass2: degree-bucket counting-sort scatter -> perm ----------------
__global__ __launch_bounds__(256) void perm_kernel(
    const int* __restrict__ cnt, const int* __restrict__ hist,
    int* __restrict__ cursor, int* __restrict__ perm, int n) {
  __shared__ int lh[NBKT], lbase[NBKT];
  int t = threadIdx.x;
  if (t < NBKT) lh[t] = 0;
  __syncthreads();
  int node = blockIdx.x * 256 + t;
  int bkt = 0, idx = 0;
  if (node < n) {
    bkt = bucket_of(cnt[node]);
    idx = atomicAdd(&lh[bkt], 1);
  }
  __syncthreads();
  if (t < NBKT) {
    int pre = 0;
#pragma unroll
    for (int k = 0; k < NBKT; ++k)
      if (k < t) pre += hist[k];
    lbase[t] = pre + atomicAdd(&cursor[t], lh[t]);
  }
  __syncthreads();
  if (node < n) perm[lbase[bkt] + idx] = node;
}

// ---------------- conv layers 1-2: degree-uniform gather + MFMA (R4-proven config) ----------------
// S = dc*(sum_nbr Xs[r] + Xs[node]); out = dc*relu((S@W^T + wsum*bl)*invdeg + bc).
// Plain launch bounds: VGPR ~80, no spills (R5 lesson: pinning waves caps VGPR -> scratch
// thrash, 262 MB writes). node = perm[gid]: degree-uniform waves, descending-length first.
__global__ __launch_bounds__(256) void conv_fused(
    const int* __restrict__ cnt, const int* __restrict__ ell,
    const int* __restrict__ perm,
    const ushort* __restrict__ Xs, const ushort* __restrict__ Wh,
    const float* __restrict__ wsum, const float* __restrict__ bl,
    const float* __restrict__ bc, ushort* __restrict__ OUT, int n) {
  const int t = threadIdx.x;
  const int w = t >> 6, lane = t & 63, quad = lane >> 4, cl = lane & 15;
  const int gid = blockIdx.x * 64 + w * 16 + cl;
  const bool valid = gid < n;
  const int node = valid ? perm[gid] : 0;

  float acc[4][8];
#pragma unroll
  for (int ks = 0; ks < 4; ++ks)
#pragma unroll
    for (int q = 0; q < 8; ++q) acc[ks][q] = 0.f;

  float dc = 1.f, id = 1.f;
  int nIt = 0;
  if (valid) {
    int cv = cnt[node];
    float d = (float)(cv + 1);
    dc = rsqrtf(d);
    id = 1.0f / d;
    int lim = cv < ELLCAP ? cv : ELLCAP;
    nIt = (lim + 3) >> 2;
  }
  const int4* ep = (const int4*)&ell[(size_t)node * ELLCAP];
  const int qoff = quad * 8;

  if (nIt > 0) {
    int4 rr = ep[0];
    for (int it = 0; it < nIt; ++it) {
      const ushort* r0 = &Xs[(size_t)rr.x * F + qoff];
      const ushort* r1 = &Xs[(size_t)rr.y * F + qoff];
      const ushort* r2 = &Xs[(size_t)rr.z * F + qoff];
      const ushort* r3 = &Xs[(size_t)rr.w * F + qoff];
      short8 v[4][4];
#pragma unroll
      for (int ks = 0; ks < 4; ++ks) {
        v[0][ks] = *(const short8*)&r0[ks * 32];
        v[1][ks] = *(const short8*)&r1[ks * 32];
        v[2][ks] = *(const short8*)&r2[ks * 32];
        v[3][ks] = *(const short8*)&r3[ks * 32];
      }
      int jn = (it + 1 < nIt) ? it + 1 : it;
      rr = ep[jn];  // prefetch next indices while rows are in flight
#pragma unroll
      for (int ks = 0; ks < 4; ++ks)
#pragma unroll
        for (int q = 0; q < 8; ++q) {
          float t0 = bf2f((ushort)v[0][ks][q]) + bf2f((ushort)v[1][ks][q]);
          float t1 = bf2f((ushort)v[2][ks][q]) + bf2f((ushort)v[3][ks][q]);
          acc[ks][q] += t0 + t1;
        }
    }
  }

  short8 sfrag[4];
  if (valid) {
    const ushort* sq = &Xs[(size_t)node * F + qoff];
#pragma unroll
    for (int ks = 0; ks < 4; ++ks) {
      short8 sv = *(const short8*)&sq[ks * 32];
      ushort o[8];
#pragma unroll
      for (int q = 0; q < 8; ++q)
        o[q] = f2bf(dc * (acc[ks][q] + bf2f((ushort)sv[q])));
      sfrag[ks] = *(short8*)o;
    }
  } else {
#pragma unroll
    for (int ks = 0; ks < 4; ++ks) sfrag[ks] = (short8){0, 0, 0, 0, 0, 0, 0, 0};
  }

  float4v co[8];
#pragma unroll
  for (int mt = 0; mt < 8; ++mt) co[mt] = (float4v){0.f, 0.f, 0.f, 0.f};
  const int sl = swz(lane);
#pragma unroll
  for (int ks = 0; ks < 4; ++ks) {
    const int base2 = ((ks >> 1) * 1024 + (ks & 1) * 64 + sl) * 8;
#pragma unroll
    for (int mt = 0; mt < 8; ++mt) {
      short8 a_h = *(const short8*)&Wh[base2 + mt * 1024];
      co[mt] = __builtin_amdgcn_mfma_f32_16x16x32_bf16(a_h, sfrag[ks], co[mt], 0, 0, 0);
    }
  }

  if (valid) {
    float ws = wsum[node];
#pragma unroll
    for (int mt = 0; mt < 8; ++mt) {
      float4 blv = *(const float4*)&bl[mt * 16 + quad * 4];
      float4 bcv = *(const float4*)&bc[mt * 16 + quad * 4];
      float v0 = fmaxf((co[mt][0] + ws * blv.x) * id + bcv.x, 0.f) * dc;
      float v1 = fmaxf((co[mt][1] + ws * blv.y) * id + bcv.y, 0.f) * dc;
      float v2 = fmaxf((co[mt][2] + ws * blv.z) * id + bcv.z, 0.f) * dc;
      float v3 = fmaxf((co[mt][3] + ws * blv.w) * id + bcv.w, 0.f) * dc;
      ushort o[4] = {f2bf(v0), f2bf(v1), f2bf(v2), f2bf(v3)};
      *(ushort4*)&OUT[(size_t)node * F + mt * 16 + quad * 4] = *(ushort4*)o;
    }
  }
}

// ---------------- conv3 + dense head + log_softmax, fully fused, zero barriers ----------------
// Gather+MFMA(W3)+epilogue as above (unscaled). Then per-wave LDS exchange (C-layout ->
// B-fragment), lin1 MFMA, second exchange, lin2 (hi+lo) + log-softmax. All LDS traffic
// wave-private; out rows routed via __shfl over perm.
__global__ __launch_bounds__(256) void conv_head(
    const int* __restrict__ cnt, const int* __restrict__ ell,
    const int* __restrict__ perm,
    const ushort* __restrict__ Xs, const ushort* __restrict__ Wh3,
    const float* __restrict__ wsum, const float* __restrict__ bl3,
    const float* __restrict__ bc3,
    const ushort* __restrict__ Wl1h, const float* __restrict__ bli1,
    const ushort* __restrict__ W2h, const ushort* __restrict__ W2l,
    const float* __restrict__ b2, float* __restrict__ out, int n) {
  __shared__ ushort sH[8192];  // 16 KB: 4 waves x 16 rows x 128 bf16 (per-wave private)
  const int t = threadIdx.x;
  const int w = t >> 6, lane = t & 63, quad = lane >> 4, cl = lane & 15;
  const int sl = swz(lane);
  const int qoff = quad * 8;
  char* sHb = (char*)sH;

  const int gid = blockIdx.x * 64 + w * 16 + cl;
  const bool valid = gid < n;
  const int node = valid ? perm[gid] : 0;

  // ---- gather ----
  float acc[4][8];
#pragma unroll
  for (int ks = 0; ks < 4; ++ks)
#pragma unroll
    for (int q = 0; q < 8; ++q) acc[ks][q] = 0.f;

  float dc = 1.f, id = 1.f, ws = 0.f;
  int nIt = 0;
  if (valid) {
    int cv = cnt[node];
    float d = (float)(cv + 1);
    dc = rsqrtf(d);
    id = 1.0f / d;
    ws = wsum[node];
    int lim = cv < ELLCAP ? cv : ELLCAP;
    nIt = (lim + 3) >> 2;
  }
  const int4* ep = (const int4*)&ell[(size_t)node * ELLCAP];

  if (nIt > 0) {
    int4 rr = ep[0];
    for (int it = 0; it < nIt; ++it) {
      const ushort* r0 = &Xs[(size_t)rr.x * F + qoff];
      const ushort* r1 = &Xs[(size_t)rr.y * F + qoff];
      const ushort* r2 = &Xs[(size_t)rr.z * F + qoff];
      const ushort* r3 = &Xs[(size_t)rr.w * F + qoff];
      short8 v[4][4];
#pragma unroll
      for (int ks = 0; ks < 4; ++ks) {
        v[0][ks] = *(const short8*)&r0[ks * 32];
        v[1][ks] = *(const short8*)&r1[ks * 32];
        v[2][ks] = *(const short8*)&r2[ks * 32];
        v[3][ks] = *(const short8*)&r3[ks * 32];
      }
      int jn = (it + 1 < nIt) ? it + 1 : it;
      rr = ep[jn];
#pragma unroll
      for (int ks = 0; ks < 4; ++ks)
#pragma unroll
        for (int q = 0; q < 8; ++q) {
          float t0 = bf2f((ushort)v[0][ks][q]) + bf2f((ushort)v[1][ks][q]);
          float t1 = bf2f((ushort)v[2][ks][q]) + bf2f((ushort)v[3][ks][q]);
          acc[ks][q] += t0 + t1;
        }
    }
  }

  short8 sfrag[4];
  if (valid) {
    const ushort* sq = &Xs[(size_t)node * F + qoff];
#pragma unroll
    for (int ks = 0; ks < 4; ++ks) {
      short8 sv = *(const short8*)&sq[ks * 32];
      ushort o[8];
#pragma unroll
      for (int q = 0; q < 8; ++q)
        o[q] = f2bf(dc * (acc[ks][q] + bf2f((ushort)sv[q])));
      sfrag[ks] = *(short8*)o;
    }
  } else {
#pragma unroll
    for (int ks = 0; ks < 4; ++ks) sfrag[ks] = (short8){0, 0, 0, 0, 0, 0, 0, 0};
  }

  // ---- conv3 MFMA ----
  float4v co[8];
#pragma unroll
  for (int mt = 0; mt < 8; ++mt) co[mt] = (float4v){0.f, 0.f, 0.f, 0.f};
#pragma unroll
  for (int ks = 0; ks < 4; ++ks) {
    const int base2 = ((ks >> 1) * 1024 + (ks & 1) * 64 + sl) * 8;
#pragma unroll
    for (int mt = 0; mt < 8; ++mt) {
      short8 a_h = *(const short8*)&Wh3[base2 + mt * 1024];
      co[mt] = __builtin_amdgcn_mfma_f32_16x16x32_bf16(a_h, sfrag[ks], co[mt], 0, 0, 0);
    }
  }

  // ---- exchange 1: conv3 epilogue -> LDS (A rows, bf16, swizzled) ----
#pragma unroll
  for (int mt = 0; mt < 8; ++mt) {
    float4 blv = *(const float4*)&bl3[mt * 16 + quad * 4];
    float4 bcv = *(const float4*)&bc3[mt * 16 + quad * 4];
    ushort o[4];
    o[0] = f2bf(fmaxf((co[mt][0] + ws * blv.x) * id + bcv.x, 0.f));
    o[1] = f2bf(fmaxf((co[mt][1] + ws * blv.y) * id + bcv.y, 0.f));
    o[2] = f2bf(fmaxf((co[mt][2] + ws * blv.z) * id + bcv.z, 0.f));
    o[3] = f2bf(fmaxf((co[mt][3] + ws * blv.w) * id + bcv.w, 0.f));
    int ch = (mt * 2 + (quad >> 1)) ^ cl;
    *(ushort4*)&sHb[w * 4096 + cl * 256 + ch * 16 + (quad & 1) * 8] = *(ushort4*)o;
  }

  // ---- lin1: h = relu(A @ Wl1^T + bli1) ----
  float4v acc1[8];
#pragma unroll
  for (int mt = 0; mt < 8; ++mt) acc1[mt] = (float4v){0.f, 0.f, 0.f, 0.f};
#pragma unroll
  for (int ks = 0; ks < 4; ++ks) {
    int ch2 = (ks * 4 + quad) ^ cl;
    short8 bfr = *(short8*)&sHb[w * 4096 + cl * 256 + ch2 * 16];
    const int base2 = ((ks >> 1) * 1024 + (ks & 1) * 64 + sl) * 8;
#pragma unroll
    for (int mt = 0; mt < 8; ++mt) {
      short8 a_h = *(const short8*)&Wl1h[base2 + mt * 1024];
      acc1[mt] = __builtin_amdgcn_mfma_f32_16x16x32_bf16(a_h, bfr, acc1[mt], 0, 0, 0);
    }
  }

  // ---- exchange 2: h -> LDS (same swizzle, same region) ----
#pragma unroll
  for (int mt = 0; mt < 8; ++mt) {
    float4 bv = *(const float4*)&bli1[mt * 16 + quad * 4];
    ushort o[4];
    o[0] = f2bf(fmaxf(acc1[mt][0] + bv.x, 0.f));
    o[1] = f2bf(fmaxf(acc1[mt][1] + bv.y, 0.f));
    o[2] = f2bf(fmaxf(acc1[mt][2] + bv.z, 0.f));
    o[3] = f2bf(fmaxf(acc1[mt][3] + bv.w, 0.f));
    int ch = (mt * 2 + (quad >> 1)) ^ cl;
    *(ushort4*)&sHb[w * 4096 + cl * 256 + ch * 16 + (quad & 1) * 8] = *(ushort4*)o;
  }

  // ---- lin2 (hi+lo) + log_softmax ----
  float4v accl[3];
#pragma unroll
  for (int ct = 0; ct < 3; ++ct) accl[ct] = (float4v){0.f, 0.f, 0.f, 0.f};
#pragma unroll
  for (int ks = 0; ks < 4; ++ks) {
    int ch2 = (ks * 4 + quad) ^ cl;
    short8 a = *(short8*)&sHb[w * 4096 + cl * 256 + ch2 * 16];
#pragma unroll
    for (int ct = 0; ct < 3; ++ct) {
      int chunk = ((ct * 4 + ks) * 64 + lane) * 8;
      short8 b_h = *(const short8*)&W2h[chunk];
      short8 b_l = *(const short8*)&W2l[chunk];
      accl[ct] = __builtin_amdgcn_mfma_f32_16x16x32_bf16(a, b_h, accl[ct], 0, 0, 0);
      accl[ct] = __builtin_amdgcn_mfma_f32_16x16x32_bf16(a, b_l, accl[ct], 0, 0, 0);
    }
  }

  float b0 = b2[cl];
  float b1 = b2[16 + cl];
  float b2v = (32 + cl < C_CLS) ? b2[32 + cl] : -1e30f;
  float lse[4];
#pragma unroll
  for (int reg = 0; reg < 4; ++reg) {
    float v0 = accl[0][reg] + b0;
    float v1 = accl[1][reg] + b1;
    float v2 = accl[2][reg] + b2v;
    accl[0][reg] = v0; accl[1][reg] = v1; accl[2][reg] = v2;
    float m = fmaxf(fmaxf(v0, v1), v2);
#pragma unroll
    for (int o = 1; o < 16; o <<= 1) m = fmaxf(m, __shfl_xor(m, o));
    float s = __expf(v0 - m) + __expf(v1 - m) + __expf(v2 - m);
#pragma unroll
    for (int o = 1; o < 16; o <<= 1) s += __shfl_xor(s, o);
    lse[reg] = logf(s) + m;
  }
  int vn = valid ? node : -1;
#pragma unroll
  for (int reg = 0; reg < 4; ++reg) {
    int s = quad * 4 + reg;          // node slot within the wave's 16-row tile
    int gn = __shfl(vn, s);
    if (gn >= 0) {
      out[(size_t)gn * C_CLS + cl] = accl[0][reg] - lse[reg];
      out[(size_t)gn * C_CLS + 16 + cl] = accl[1][reg] - lse[reg];
      if (cl < 8) out[(size_t)gn * C_CLS + 32 + cl] = accl[2][reg] - lse[reg];
    }
  }
}

extern "C" void kernel_launch(void* const* d_in, const int* in_sizes, int n_in,
                              void* d_out, int out_size, void* d_ws, size_t ws_size,
                              hipStream_t stream) {
  const float* x    = (const float*)d_in[0];
  const int*   ei   = (const int*)d_in[1];
  const float* imp  = (const float*)d_in[2];
  const float* W1   = (const float*)d_in[3];
  const float* bl1  = (const float*)d_in[4];
  const float* bc1  = (const float*)d_in[5];
  const float* W2   = (const float*)d_in[6];
  const float* bl2  = (const float*)d_in[7];
  const float* bc2  = (const float*)d_in[8];
  const float* W3   = (const float*)d_in[9];
  const float* bl3  = (const float*)d_in[10];
  const float* bc3  = (const float*)d_in[11];
  const float* Wl1  = (const float*)d_in[12];
  const float* bli1 = (const float*)d_in[13];
  const float* Wl2  = (const float*)d_in[14];
  const float* bli2 = (const float*)d_in[15];
  float* out = (float*)d_out;

  const int N = in_sizes[0] / F;      // 100000
  const int E = in_sizes[1] / 2;      // 600000

  // ping-pong buffers have N+1 rows; row N is the shared zero row for ELL tails
  ushort* A16 = (ushort*)d_ws;                     // (N+1)*F
  ushort* B16 = A16 + (size_t)(N + 1) * F;         // (N+1)*F
  ushort* WhP = B16 + (size_t)(N + 1) * F;         // 8192*8
  ushort* W2hH = WhP + 65536;                      // 768*8
  ushort* W2lH = W2hH + 6144;                      // 768*8
  float* wsum = (float*)(W2lH + 6144);             // N
  int*   cnt  = (int*)(wsum + N);                  // N (packed)
  int*   hist = cnt + N;                           // 9
  int*   cursor = hist + NBKT;                     // 9
  int*   perm = cursor + NBKT;                     // N
  int*   ell  = perm + N;                          // 32N

  const int* rowv = ei;
  const int* colv = ei + E;

  int nbE  = (E + 255) / 256;
  int nbW  = (N + 255) / 256;          // prepass wsum/hist blocks
  int nbX  = (N * F + 2047) / 2048;    // prepass x->Xs blocks (8 elems/thread)
  int nbCv = (N + 63) / 64;            // conv blocks (64 nodes each)

  // ---- one-time prep ----
  hipMemsetAsync(cnt, 0, ((size_t)N + 2 * NBKT) * sizeof(int), stream);
  setup_kernel<<<NWSPLIT + nbE, 256, 0, stream>>>(
      W1, imp, W2, W3, Wl1, Wl2, WhP, W2hH, W2lH, rowv, colv, cnt, ell, E, N);
  prepass_kernel<<<nbW + nbX + 1, 256, 0, stream>>>(
      x, cnt, ell, wsum, hist, B16, A16, N, nbW, nbX);
  perm_kernel<<<nbW, 256, 0, stream>>>(cnt, hist, cursor, perm, N);

  // ---- conv layers 1-2: R4-proven configuration ----
  conv_fused<<<nbCv, 256, 0, stream>>>(cnt, ell, perm, B16, WhP,         wsum, bl1, bc1, A16, N);
  conv_fused<<<nbCv, 256, 0, stream>>>(cnt, ell, perm, A16, WhP + 16384, wsum, bl2, bc2, B16, N);

  // ---- conv layer 3 + dense head + log_softmax, fully fused ----
  conv_head<<<nbCv, 256, 0, stream>>>(cnt, ell, perm, B16, WhP + 32768, wsum, bl3, bc3,
                                      WhP + 49152, bli1, W2hH, W2lH, bli2, out, N);
}

// Round 7
// 338.870 us; speedup vs baseline: 1.6848x; 1.0363x over previous
//
#include <hip/hip_runtime.h>
#include <hip/hip_bf16.h>

#define F 128
#define C_CLS 40
#define NWSPLIT 35
#define ELLCAP 32
#define NBKT 9

typedef __attribute__((ext_vector_type(8))) short short8;
typedef __attribute__((ext_vector_type(4))) float float4v;
typedef unsigned short ushort;

__device__ inline float bf2f(ushort u) {
  unsigned int x = ((unsigned int)u) << 16;
  return __builtin_bit_cast(float, x);
}
__device__ inline ushort f2bf(float f) {
  __hip_bfloat16 h = __float2bfloat16(f);
  return __builtin_bit_cast(ushort, h);
}
__device__ inline void split_bf16(float f, ushort& hi, ushort& lo) {
  hi = f2bf(f);
  lo = f2bf(f - bf2f(hi));
}
__device__ inline int swz(int lane) { return lane ^ ((lane >> 4) & 3); }
// bucket: descending by iteration count (long waves launch first)
__device__ inline int bucket_of(int cv) {
  int lim = cv < ELLCAP ? cv : ELLCAP;
  int nIt = (lim + 3) >> 2;           // 0..8
  return 8 - nIt;                     // 0 = deg 29..32
}

// ---------------- setup (heterogeneous): weight-split | ELL fill ----------------
__global__ __launch_bounds__(256) void setup_kernel(
    const float* __restrict__ W1, const float* __restrict__ imp,
    const float* __restrict__ W2, const float* __restrict__ W3,
    const float* __restrict__ Wl1, const float* __restrict__ Wh2,
    ushort* __restrict__ WhP,
    ushort* __restrict__ W2hH, ushort* __restrict__ W2lH,
    const int* __restrict__ row, const int* __restrict__ col,
    int* __restrict__ cnt, int* __restrict__ ell,
    int ne, int n) {
  int b = blockIdx.x;
  if (b < NWSPLIT) {
    int ci = b * 256 + threadIdx.x;
    if (ci < 8192) {
      const float* src[4] = {W1, W2, W3, Wl1};
      int p = ci >> 11, c = ci & 2047;
      int kc = c >> 10, ct = (c >> 7) & 7, ks = (c >> 6) & 1, ln = c & 63;
      int dl = swz(ln);
      int colw = ct * 16 + (dl & 15);
      int k = kc * 64 + ks * 32 + (dl >> 4) * 8;
      float4 f0 = *(const float4*)&src[p][(size_t)colw * F + k];
      float4 f1 = *(const float4*)&src[p][(size_t)colw * F + k + 4];
      float v[8] = {f0.x, f0.y, f0.z, f0.w, f1.x, f1.y, f1.z, f1.w};
      if (p == 0) {
        float4 i0 = *(const float4*)&imp[k];
        float4 i1 = *(const float4*)&imp[k + 4];
        v[0] *= i0.x; v[1] *= i0.y; v[2] *= i0.z; v[3] *= i0.w;
        v[4] *= i1.x; v[5] *= i1.y; v[6] *= i1.z; v[7] *= i1.w;
      }
      ushort hi[8];
#pragma unroll
      for (int j = 0; j < 8; ++j) hi[j] = f2bf(v[j]);
      *(short8*)&WhP[(size_t)ci * 8] = *(short8*)hi;
    } else if (ci < 8192 + 768) {
      int c = ci - 8192;
      int ct = c >> 8, ks = (c >> 6) & 3, ln = c & 63;
      int colw = ct * 16 + (ln & 15);
      int k = ks * 32 + (ln >> 4) * 8;
      float v[8];
      if (colw < C_CLS) {
        float4 f0 = *(const float4*)&Wh2[(size_t)colw * F + k];
        float4 f1 = *(const float4*)&Wh2[(size_t)colw * F + k + 4];
        v[0] = f0.x; v[1] = f0.y; v[2] = f0.z; v[3] = f0.w;
        v[4] = f1.x; v[5] = f1.y; v[6] = f1.z; v[7] = f1.w;
      } else {
#pragma unroll
        for (int j = 0; j < 8; ++j) v[j] = 0.f;
      }
      ushort hi[8], lo[8];
#pragma unroll
      for (int j = 0; j < 8; ++j) split_bf16(v[j], hi[j], lo[j]);
      *(short8*)&W2hH[(size_t)c * 8] = *(short8*)hi;
      *(short8*)&W2lH[(size_t)c * 8] = *(short8*)lo;
    }
  } else {
    int e = (b - NWSPLIT) * 256 + threadIdx.x;
    if (e < ne) {
      int r = row[e], c = col[e];
      int p = atomicAdd(&cnt[c], 1);
      if (p < ELLCAP) ell[(size_t)c * ELLCAP + p] = r;
    }
  }
}

// ---------------- prepass1: wsum + ELL tail rewrite + bucket hist | x -> Xs | zero rows ----
__global__ __launch_bounds__(256) void prepass_kernel(
    const float* __restrict__ x, const int* __restrict__ cnt,
    int* __restrict__ ell, float* __restrict__ wsum, int* __restrict__ hist,
    ushort* __restrict__ Xs, ushort* __restrict__ Az,
    int n, int nbW, int nbX) {
  int b = blockIdx.x;
  if (b < nbW) {
    __shared__ int lh[NBKT];
    int t = threadIdx.x;
    if (t < NBKT) lh[t] = 0;
    __syncthreads();
    int node = b * 256 + t;
    if (node < n) {
      int cv = cnt[node];
      int lim = cv < ELLCAP ? cv : ELLCAP;
      int lim4 = (lim + 3) & ~3;
      float gs = 0.f;
      const int4* ep = (const int4*)&ell[(size_t)node * ELLCAP];
      for (int base = 0; base < lim; base += 4) {
        int4 rr = ep[base >> 2];
        bool p1 = base + 1 < lim, p2 = base + 2 < lim, p3 = base + 3 < lim;
        int r1 = p1 ? rr.y : rr.x;
        int r2 = p2 ? rr.z : rr.x;
        int r3 = p3 ? rr.w : rr.x;
        float g0 = rsqrtf((float)(cnt[rr.x] + 1));
        float g1 = p1 ? rsqrtf((float)(cnt[r1] + 1)) : 0.f;
        float g2 = p2 ? rsqrtf((float)(cnt[r2] + 1)) : 0.f;
        float g3 = p3 ? rsqrtf((float)(cnt[r3] + 1)) : 0.f;
        gs += (g0 + g1) + (g2 + g3);
      }
      float d = (float)(cv + 1);
      wsum[node] = rsqrtf(d) * gs + 1.0f / d;
      for (int p = lim; p < lim4; ++p) ell[(size_t)node * ELLCAP + p] = n;
      atomicAdd(&lh[bucket_of(cv)], 1);
    }
    __syncthreads();
    if (t < NBKT) atomicAdd(&hist[t], lh[t]);
  } else if (b < nbW + nbX) {
    size_t i = (size_t)(b - nbW) * 2048 + (size_t)threadIdx.x * 8;
    if (i < (size_t)n * F) {
      int node = (int)(i >> 7);
      float dc = rsqrtf((float)(cnt[node] + 1));
      float4 f0 = *(const float4*)&x[i];
      float4 f1 = *(const float4*)&x[i + 4];
      ushort o[8] = {f2bf(dc * f0.x), f2bf(dc * f0.y), f2bf(dc * f0.z), f2bf(dc * f0.w),
                     f2bf(dc * f1.x), f2bf(dc * f1.y), f2bf(dc * f1.z), f2bf(dc * f1.w)};
      *(short8*)&Xs[i] = *(short8*)o;
    }
  } else {
    int t = threadIdx.x;
    short8 z = (short8){0, 0, 0, 0, 0, 0, 0, 0};
    if (t < 16) *(short8*)&Xs[(size_t)n * F + t * 8] = z;
    else if (t < 32) *(short8*)&Az[(size_t)n * F + (t - 16) * 8] = z;
  }
}

// ---------------- prepass2: degree-bucket counting-sort scatter -> perm ----------------
__global__ __launch_bounds__(256) void perm_kernel(
    const int* __restrict__ cnt, const int* __restrict__ hist,
    int* __restrict__ cursor, int* __restrict__ perm, int n) {
  __shared__ int lh[NBKT], lbase[NBKT];
  int t = threadIdx.x;
  if (t < NBKT) lh[t] = 0;
  __syncthreads();
  int node = blockIdx.x * 256 + t;
  int bkt = 0, idx = 0;
  if (node < n) {
    bkt = bucket_of(cnt[node]);
    idx = atomicAdd(&lh[bkt], 1);
  }
  __syncthreads();
  if (t < NBKT) {
    int pre = 0;
#pragma unroll
    for (int k = 0; k < NBKT; ++k)
      if (k < t) pre += hist[k];
    lbase[t] = pre + atomicAdd(&cursor[t], lh[t]);
  }
  __syncthreads();
  if (node < n) perm[lbase[bkt] + idx] = node;
}

// ---------------- LEAN gather: pure row-sum, phase-pure, VGPR-minimal ----------------
// S[node] = dc * (sum_nbr Xin[r] + Xin[node]), bf16. One 16-lane group per node,
// one 16B load per lane per row, 8-float acc. No MFMA, no LDS -> max waves/SIMD ->
// max outstanding random reads (the R6 lesson: mixing gather with MFMA/VGPR-heavy
// work halves gather concurrency). Degree-binned perm keeps waves uniform.
__global__ __launch_bounds__(256) void gather_lean(
    const int* __restrict__ cnt, const int* __restrict__ ell,
    const int* __restrict__ perm,
    const ushort* __restrict__ Xin, ushort* __restrict__ S, int n) {
  int g = blockIdx.x * 16 + (threadIdx.x >> 4);
  if (g >= n) return;
  int node = perm[g];
  int j = (threadIdx.x & 15) * 8;
  int cv = cnt[node];
  float dc = rsqrtf((float)(cv + 1));
  int lim = cv < ELLCAP ? cv : ELLCAP;
  int lim4 = (lim + 3) & ~3;
  const int4* ep = (const int4*)&ell[(size_t)node * ELLCAP];
  float a0[8] = {0, 0, 0, 0, 0, 0, 0, 0};
  float a1[8] = {0, 0, 0, 0, 0, 0, 0, 0};
  float a2[8] = {0, 0, 0, 0, 0, 0, 0, 0};
  float a3[8] = {0, 0, 0, 0, 0, 0, 0, 0};
  for (int base = 0; base < lim4; base += 4) {
    int4 rr = ep[base >> 2];   // tails pre-rewritten to zero-row n: no gating
    short8 v0 = *(const short8*)&Xin[(size_t)rr.x * F + j];
    short8 v1 = *(const short8*)&Xin[(size_t)rr.y * F + j];
    short8 v2 = *(const short8*)&Xin[(size_t)rr.z * F + j];
    short8 v3 = *(const short8*)&Xin[(size_t)rr.w * F + j];
#pragma unroll
    for (int q = 0; q < 8; ++q) {
      a0[q] += bf2f((ushort)v0[q]);
      a1[q] += bf2f((ushort)v1[q]);
      a2[q] += bf2f((ushort)v2[q]);
      a3[q] += bf2f((ushort)v3[q]);
    }
  }
  short8 sv = *(const short8*)&Xin[(size_t)node * F + j];
  ushort o[8];
#pragma unroll
  for (int q = 0; q < 8; ++q) {
    float s = (a0[q] + a1[q]) + (a2[q] + a3[q]) + bf2f((ushort)sv[q]);
    o[q] = f2bf(dc * s);
  }
  *(short8*)&S[(size_t)node * F + j] = *(short8*)o;
}

// ---------------- streaming GEMM (layers 1-2): S -> dc*relu((S@W^T + wsum*bl)*id + bc) ----
// Natural node order (coalesced). Weights direct from L2. Output pre-scaled by dc
// for the next layer's gather.
__global__ __launch_bounds__(256) void gemm_mid(
    const ushort* __restrict__ S, const ushort* __restrict__ Wh,
    const int* __restrict__ cnt, const float* __restrict__ wsum,
    const float* __restrict__ bl, const float* __restrict__ bc,
    ushort* __restrict__ OUT, int n) {
  const int t = threadIdx.x;
  const int w = t >> 6, lane = t & 63, quad = lane >> 4, cl = lane & 15;
  const int gr = blockIdx.x * 64 + w * 16 + cl;
  const bool valid = gr < n;

  short8 b[4];
  if (valid) {
    const ushort* sq = &S[(size_t)gr * F + quad * 8];
#pragma unroll
    for (int ks = 0; ks < 4; ++ks) b[ks] = *(const short8*)&sq[ks * 32];
  } else {
#pragma unroll
    for (int ks = 0; ks < 4; ++ks) b[ks] = (short8){0, 0, 0, 0, 0, 0, 0, 0};
  }

  float4v co[8];
#pragma unroll
  for (int mt = 0; mt < 8; ++mt) co[mt] = (float4v){0.f, 0.f, 0.f, 0.f};
  const int sl = swz(lane);
#pragma unroll
  for (int ks = 0; ks < 4; ++ks) {
    const int base2 = ((ks >> 1) * 1024 + (ks & 1) * 64 + sl) * 8;
#pragma unroll
    for (int mt = 0; mt < 8; ++mt) {
      short8 a_h = *(const short8*)&Wh[base2 + mt * 1024];
      co[mt] = __builtin_amdgcn_mfma_f32_16x16x32_bf16(a_h, b[ks], co[mt], 0, 0, 0);
    }
  }

  if (valid) {
    float d = (float)(cnt[gr] + 1);
    float dc = rsqrtf(d);
    float id = 1.0f / d;
    float ws = wsum[gr];
#pragma unroll
    for (int mt = 0; mt < 8; ++mt) {
      float4 blv = *(const float4*)&bl[mt * 16 + quad * 4];
      float4 bcv = *(const float4*)&bc[mt * 16 + quad * 4];
      float v0 = fmaxf((co[mt][0] + ws * blv.x) * id + bcv.x, 0.f) * dc;
      float v1 = fmaxf((co[mt][1] + ws * blv.y) * id + bcv.y, 0.f) * dc;
      float v2 = fmaxf((co[mt][2] + ws * blv.z) * id + bcv.z, 0.f) * dc;
      float v3 = fmaxf((co[mt][3] + ws * blv.w) * id + bcv.w, 0.f) * dc;
      ushort o[4] = {f2bf(v0), f2bf(v1), f2bf(v2), f2bf(v3)};
      *(ushort4*)&OUT[(size_t)gr * F + mt * 16 + quad * 4] = *(ushort4*)o;
    }
  }
}

// ---------------- streaming GEMM3 + lin1 + lin2 + log_softmax (natural order) ----------------
// Reads S3 rows coalesced; conv3 MFMA -> per-wave LDS exchange -> lin1 -> exchange ->
// lin2 (hi+lo) + softmax. Zero barriers (wave-private LDS).
__global__ __launch_bounds__(256) void head3(
    const ushort* __restrict__ S, const ushort* __restrict__ Wh3,
    const int* __restrict__ cnt, const float* __restrict__ wsum,
    const float* __restrict__ bl3, const float* __restrict__ bc3,
    const ushort* __restrict__ Wl1h, const float* __restrict__ bli1,
    const ushort* __restrict__ W2h, const ushort* __restrict__ W2l,
    const float* __restrict__ b2, float* __restrict__ out, int n) {
  __shared__ ushort sH[8192];  // 16 KB: 4 waves x 16 rows x 128 bf16 (wave-private)
  const int t = threadIdx.x;
  const int w = t >> 6, lane = t & 63, quad = lane >> 4, cl = lane & 15;
  const int sl = swz(lane);
  char* sHb = (char*)sH;

  const int row0 = blockIdx.x * 64 + w * 16;
  const int gr = row0 + cl;
  const bool valid = gr < n;

  short8 b[4];
  float id = 1.f, ws = 0.f;
  if (valid) {
    const ushort* sq = &S[(size_t)gr * F + quad * 8];
#pragma unroll
    for (int ks = 0; ks < 4; ++ks) b[ks] = *(const short8*)&sq[ks * 32];
    id = 1.0f / (float)(cnt[gr] + 1);
    ws = wsum[gr];
  } else {
#pragma unroll
    for (int ks = 0; ks < 4; ++ks) b[ks] = (short8){0, 0, 0, 0, 0, 0, 0, 0};
  }

  // ---- conv3 MFMA ----
  float4v co[8];
#pragma unroll
  for (int mt = 0; mt < 8; ++mt) co[mt] = (float4v){0.f, 0.f, 0.f, 0.f};
#pragma unroll
  for (int ks = 0; ks < 4; ++ks) {
    const int base2 = ((ks >> 1) * 1024 + (ks & 1) * 64 + sl) * 8;
#pragma unroll
    for (int mt = 0; mt < 8; ++mt) {
      short8 a_h = *(const short8*)&Wh3[base2 + mt * 1024];
      co[mt] = __builtin_amdgcn_mfma_f32_16x16x32_bf16(a_h, b[ks], co[mt], 0, 0, 0);
    }
  }

  // ---- exchange 1: conv3 epilogue -> LDS (rows, bf16, swizzled) ----
#pragma unroll
  for (int mt = 0; mt < 8; ++mt) {
    float4 blv = *(const float4*)&bl3[mt * 16 + quad * 4];
    float4 bcv = *(const float4*)&bc3[mt * 16 + quad * 4];
    ushort o[4];
    o[0] = f2bf(fmaxf((co[mt][0] + ws * blv.x) * id + bcv.x, 0.f));
    o[1] = f2bf(fmaxf((co[mt][1] + ws * blv.y) * id + bcv.y, 0.f));
    o[2] = f2bf(fmaxf((co[mt][2] + ws * blv.z) * id + bcv.z, 0.f));
    o[3] = f2bf(fmaxf((co[mt][3] + ws * blv.w) * id + bcv.w, 0.f));
    int ch = (mt * 2 + (quad >> 1)) ^ cl;
    *(ushort4*)&sHb[w * 4096 + cl * 256 + ch * 16 + (quad & 1) * 8] = *(ushort4*)o;
  }

  // ---- lin1: h = relu(A @ Wl1^T + bli1) ----
  float4v acc1[8];
#pragma unroll
  for (int mt = 0; mt < 8; ++mt) acc1[mt] = (float4v){0.f, 0.f, 0.f, 0.f};
#pragma unroll
  for (int ks = 0; ks < 4; ++ks) {
    int ch2 = (ks * 4 + quad) ^ cl;
    short8 bfr = *(short8*)&sHb[w * 4096 + cl * 256 + ch2 * 16];
    const int base2 = ((ks >> 1) * 1024 + (ks & 1) * 64 + sl) * 8;
#pragma unroll
    for (int mt = 0; mt < 8; ++mt) {
      short8 a_h = *(const short8*)&Wl1h[base2 + mt * 1024];
      acc1[mt] = __builtin_amdgcn_mfma_f32_16x16x32_bf16(a_h, bfr, acc1[mt], 0, 0, 0);
    }
  }

  // ---- exchange 2: h -> LDS (same swizzle, same region) ----
#pragma unroll
  for (int mt = 0; mt < 8; ++mt) {
    float4 bv = *(const float4*)&bli1[mt * 16 + quad * 4];
    ushort o[4];
    o[0] = f2bf(fmaxf(acc1[mt][0] + bv.x, 0.f));
    o[1] = f2bf(fmaxf(acc1[mt][1] + bv.y, 0.f));
    o[2] = f2bf(fmaxf(acc1[mt][2] + bv.z, 0.f));
    o[3] = f2bf(fmaxf(acc1[mt][3] + bv.w, 0.f));
    int ch = (mt * 2 + (quad >> 1)) ^ cl;
    *(ushort4*)&sHb[w * 4096 + cl * 256 + ch * 16 + (quad & 1) * 8] = *(ushort4*)o;
  }

  // ---- lin2 (hi+lo) + log_softmax ----
  float4v accl[3];
#pragma unroll
  for (int ct = 0; ct < 3; ++ct) accl[ct] = (float4v){0.f, 0.f, 0.f, 0.f};
#pragma unroll
  for (int ks = 0; ks < 4; ++ks) {
    int ch2 = (ks * 4 + quad) ^ cl;
    short8 a = *(short8*)&sHb[w * 4096 + cl * 256 + ch2 * 16];
#pragma unroll
    for (int ct = 0; ct < 3; ++ct) {
      int chunk = ((ct * 4 + ks) * 64 + lane) * 8;
      short8 b_h = *(const short8*)&W2h[chunk];
      short8 b_l = *(const short8*)&W2l[chunk];
      accl[ct] = __builtin_amdgcn_mfma_f32_16x16x32_bf16(a, b_h, accl[ct], 0, 0, 0);
      accl[ct] = __builtin_amdgcn_mfma_f32_16x16x32_bf16(a, b_l, accl[ct], 0, 0, 0);
    }
  }

  float b0 = b2[cl];
  float b1 = b2[16 + cl];
  float b2v = (32 + cl < C_CLS) ? b2[32 + cl] : -1e30f;
  float lse[4];
#pragma unroll
  for (int reg = 0; reg < 4; ++reg) {
    float v0 = accl[0][reg] + b0;
    float v1 = accl[1][reg] + b1;
    float v2 = accl[2][reg] + b2v;
    accl[0][reg] = v0; accl[1][reg] = v1; accl[2][reg] = v2;
    float m = fmaxf(fmaxf(v0, v1), v2);
#pragma unroll
    for (int o = 1; o < 16; o <<= 1) m = fmaxf(m, __shfl_xor(m, o));
    float s = __expf(v0 - m) + __expf(v1 - m) + __expf(v2 - m);
#pragma unroll
    for (int o = 1; o < 16; o <<= 1) s += __shfl_xor(s, o);
    lse[reg] = logf(s) + m;
  }
#pragma unroll
  for (int reg = 0; reg < 4; ++reg) {
    int go = row0 + quad * 4 + reg;
    if (go < n) {
      out[(size_t)go * C_CLS + cl] = accl[0][reg] - lse[reg];
      out[(size_t)go * C_CLS + 16 + cl] = accl[1][reg] - lse[reg];
      if (cl < 8) out[(size_t)go * C_CLS + 32 + cl] = accl[2][reg] - lse[reg];
    }
  }
}

extern "C" void kernel_launch(void* const* d_in, const int* in_sizes, int n_in,
                              void* d_out, int out_size, void* d_ws, size_t ws_size,
                              hipStream_t stream) {
  const float* x    = (const float*)d_in[0];
  const int*   ei   = (const int*)d_in[1];
  const float* imp  = (const float*)d_in[2];
  const float* W1   = (const float*)d_in[3];
  const float* bl1  = (const float*)d_in[4];
  const float* bc1  = (const float*)d_in[5];
  const float* W2   = (const float*)d_in[6];
  const float* bl2  = (const float*)d_in[7];
  const float* bc2  = (const float*)d_in[8];
  const float* W3   = (const float*)d_in[9];
  const float* bl3  = (const float*)d_in[10];
  const float* bc3  = (const float*)d_in[11];
  const float* Wl1  = (const float*)d_in[12];
  const float* bli1 = (const float*)d_in[13];
  const float* Wl2  = (const float*)d_in[14];
  const float* bli2 = (const float*)d_in[15];
  float* out = (float*)d_out;

  const int N = in_sizes[0] / F;      // 100000
  const int E = in_sizes[1] / 2;      // 600000

  // ping-pong buffers have N+1 rows; row N is the shared zero row for ELL tails
  ushort* A16 = (ushort*)d_ws;                     // (N+1)*F
  ushort* B16 = A16 + (size_t)(N + 1) * F;         // (N+1)*F
  ushort* WhP = B16 + (size_t)(N + 1) * F;         // 8192*8
  ushort* W2hH = WhP + 65536;                      // 768*8
  ushort* W2lH = W2hH + 6144;                      // 768*8
  float* wsum = (float*)(W2lH + 6144);             // N
  int*   cnt  = (int*)(wsum + N);                  // N (packed)
  int*   hist = cnt + N;                           // 9
  int*   cursor = hist + NBKT;                     // 9
  int*   perm = cursor + NBKT;                     // N
  int*   ell  = perm + N;                          // 32N

  const int* rowv = ei;
  const int* colv = ei + E;

  int nbE  = (E + 255) / 256;
  int nbW  = (N + 255) / 256;          // prepass wsum/hist blocks
  int nbX  = (N * F + 2047) / 2048;    // prepass x->Xs blocks (8 elems/thread)
  int nbGa = (N + 15) / 16;            // lean gather blocks (16 nodes each)
  int nbGe = (N + 63) / 64;            // gemm/head blocks (64 rows each)

  // ---- one-time prep ----
  hipMemsetAsync(cnt, 0, ((size_t)N + 2 * NBKT) * sizeof(int), stream);
  setup_kernel<<<NWSPLIT + nbE, 256, 0, stream>>>(
      W1, imp, W2, W3, Wl1, Wl2, WhP, W2hH, W2lH, rowv, colv, cnt, ell, E, N);
  prepass_kernel<<<nbW + nbX + 1, 256, 0, stream>>>(
      x, cnt, ell, wsum, hist, B16, A16, N, nbW, nbX);
  perm_kernel<<<nbW, 256, 0, stream>>>(cnt, hist, cursor, perm, N);

  // ---- layer 1: lean gather (Xs=B16 -> S1=A16), streaming GEMM (A16 -> B16 scaled) ----
  gather_lean<<<nbGa, 256, 0, stream>>>(cnt, ell, perm, B16, A16, N);
  gemm_mid<<<nbGe, 256, 0, stream>>>(A16, WhP, cnt, wsum, bl1, bc1, B16, N);

  // ---- layer 2 ----
  gather_lean<<<nbGa, 256, 0, stream>>>(cnt, ell, perm, B16, A16, N);
  gemm_mid<<<nbGe, 256, 0, stream>>>(A16, WhP + 16384, cnt, wsum, bl2, bc2, B16, N);

  // ---- layer 3 gather + fused GEMM3/lin1/lin2/log_softmax ----
  gather_lean<<<nbGa, 256, 0, stream>>>(cnt, ell, perm, B16, A16, N);
  head3<<<nbGe, 256, 0, stream>>>(A16, WhP + 32768, cnt, wsum, bl3, bc3,
                                  WhP + 49152, bli1, W2hH, W2lH, bli2, out, N);
}

// Round 8
// 338.849 us; speedup vs baseline: 1.6849x; 1.0001x over previous
//
#include <hip/hip_runtime.h>
#include <hip/hip_bf16.h>

#define F 128
#define C_CLS 40
#define NWSPLIT 35
#define ELLCAP 32
#define NBKT 9

typedef __attribute__((ext_vector_type(8))) short short8;
typedef __attribute__((ext_vector_type(4))) float float4v;
typedef unsigned short ushort;

__device__ inline float bf2f(ushort u) {
  unsigned int x = ((unsigned int)u) << 16;
  return __builtin_bit_cast(float, x);
}
__device__ inline ushort f2bf(float f) {
  __hip_bfloat16 h = __float2bfloat16(f);
  return __builtin_bit_cast(ushort, h);
}
__device__ inline void split_bf16(float f, ushort& hi, ushort& lo) {
  hi = f2bf(f);
  lo = f2bf(f - bf2f(hi));
}
__device__ inline int swz(int lane) { return lane ^ ((lane >> 4) & 3); }
// bucket: descending by iteration count (long waves launch first)
__device__ inline int bucket_of(int cv) {
  int lim = cv < ELLCAP ? cv : ELLCAP;
  int nIt = (lim + 3) >> 2;           // 0..8
  return 8 - nIt;                     // 0 = deg 29..32
}

// ---------------- setup (heterogeneous): weight-split | ELL fill ----------------
__global__ __launch_bounds__(256) void setup_kernel(
    const float* __restrict__ W1, const float* __restrict__ imp,
    const float* __restrict__ W2, const float* __restrict__ W3,
    const float* __restrict__ Wl1, const float* __restrict__ Wh2,
    ushort* __restrict__ WhP,
    ushort* __restrict__ W2hH, ushort* __restrict__ W2lH,
    const int* __restrict__ row, const int* __restrict__ col,
    int* __restrict__ cnt, int* __restrict__ ell,
    int ne, int n) {
  int b = blockIdx.x;
  if (b < NWSPLIT) {
    int ci = b * 256 + threadIdx.x;
    if (ci < 8192) {
      const float* src[4] = {W1, W2, W3, Wl1};
      int p = ci >> 11, c = ci & 2047;
      int kc = c >> 10, ct = (c >> 7) & 7, ks = (c >> 6) & 1, ln = c & 63;
      int dl = swz(ln);
      int colw = ct * 16 + (dl & 15);
      int k = kc * 64 + ks * 32 + (dl >> 4) * 8;
      float4 f0 = *(const float4*)&src[p][(size_t)colw * F + k];
      float4 f1 = *(const float4*)&src[p][(size_t)colw * F + k + 4];
      float v[8] = {f0.x, f0.y, f0.z, f0.w, f1.x, f1.y, f1.z, f1.w};
      if (p == 0) {
        float4 i0 = *(const float4*)&imp[k];
        float4 i1 = *(const float4*)&imp[k + 4];
        v[0] *= i0.x; v[1] *= i0.y; v[2] *= i0.z; v[3] *= i0.w;
        v[4] *= i1.x; v[5] *= i1.y; v[6] *= i1.z; v[7] *= i1.w;
      }
      ushort hi[8];
#pragma unroll
      for (int j = 0; j < 8; ++j) hi[j] = f2bf(v[j]);
      *(short8*)&WhP[(size_t)ci * 8] = *(short8*)hi;
    } else if (ci < 8192 + 768) {
      int c = ci - 8192;
      int ct = c >> 8, ks = (c >> 6) & 3, ln = c & 63;
      int colw = ct * 16 + (ln & 15);
      int k = ks * 32 + (ln >> 4) * 8;
      float v[8];
      if (colw < C_CLS) {
        float4 f0 = *(const float4*)&Wh2[(size_t)colw * F + k];
        float4 f1 = *(const float4*)&Wh2[(size_t)colw * F + k + 4];
        v[0] = f0.x; v[1] = f0.y; v[2] = f0.z; v[3] = f0.w;
        v[4] = f1.x; v[5] = f1.y; v[6] = f1.z; v[7] = f1.w;
      } else {
#pragma unroll
        for (int j = 0; j < 8; ++j) v[j] = 0.f;
      }
      ushort hi[8], lo[8];
#pragma unroll
      for (int j = 0; j < 8; ++j) split_bf16(v[j], hi[j], lo[j]);
      *(short8*)&W2hH[(size_t)c * 8] = *(short8*)hi;
      *(short8*)&W2lH[(size_t)c * 8] = *(short8*)lo;
    }
  } else {
    int e = (b - NWSPLIT) * 256 + threadIdx.x;
    if (e < ne) {
      int r = row[e], c = col[e];
      int p = atomicAdd(&cnt[c], 1);
      if (p < ELLCAP) ell[(size_t)c * ELLCAP + p] = r;
    }
  }
}

// ---------------- prepass1: wsum + ELL tail rewrite + bucket hist | x -> Xs | zero rows ----
__global__ __launch_bounds__(256) void prepass_kernel(
    const float* __restrict__ x, const int* __restrict__ cnt,
    int* __restrict__ ell, float* __restrict__ wsum, int* __restrict__ hist,
    ushort* __restrict__ Xs, ushort* __restrict__ Az,
    int n, int nbW, int nbX) {
  int b = blockIdx.x;
  if (b < nbW) {
    __shared__ int lh[NBKT];
    int t = threadIdx.x;
    if (t < NBKT) lh[t] = 0;
    __syncthreads();
    int node = b * 256 + t;
    if (node < n) {
      int cv = cnt[node];
      int lim = cv < ELLCAP ? cv : ELLCAP;
      int lim4 = (lim + 3) & ~3;
      float gs = 0.f;
      const int4* ep = (const int4*)&ell[(size_t)node * ELLCAP];
      for (int base = 0; base < lim; base += 4) {
        int4 rr = ep[base >> 2];
        bool p1 = base + 1 < lim, p2 = base + 2 < lim, p3 = base + 3 < lim;
        int r1 = p1 ? rr.y : rr.x;
        int r2 = p2 ? rr.z : rr.x;
        int r3 = p3 ? rr.w : rr.x;
        float g0 = rsqrtf((float)(cnt[rr.x] + 1));
        float g1 = p1 ? rsqrtf((float)(cnt[r1] + 1)) : 0.f;
        float g2 = p2 ? rsqrtf((float)(cnt[r2] + 1)) : 0.f;
        float g3 = p3 ? rsqrtf((float)(cnt[r3] + 1)) : 0.f;
        gs += (g0 + g1) + (g2 + g3);
      }
      float d = (float)(cv + 1);
      wsum[node] = rsqrtf(d) * gs + 1.0f / d;
      for (int p = lim; p < lim4; ++p) ell[(size_t)node * ELLCAP + p] = n;
      atomicAdd(&lh[bucket_of(cv)], 1);
    }
    __syncthreads();
    if (t < NBKT) atomicAdd(&hist[t], lh[t]);
  } else if (b < nbW + nbX) {
    size_t i = (size_t)(b - nbW) * 2048 + (size_t)threadIdx.x * 8;
    if (i < (size_t)n * F) {
      int node = (int)(i >> 7);
      float dc = rsqrtf((float)(cnt[node] + 1));
      float4 f0 = *(const float4*)&x[i];
      float4 f1 = *(const float4*)&x[i + 4];
      ushort o[8] = {f2bf(dc * f0.x), f2bf(dc * f0.y), f2bf(dc * f0.z), f2bf(dc * f0.w),
                     f2bf(dc * f1.x), f2bf(dc * f1.y), f2bf(dc * f1.z), f2bf(dc * f1.w)};
      *(short8*)&Xs[i] = *(short8*)o;
    }
  } else {
    int t = threadIdx.x;
    short8 z = (short8){0, 0, 0, 0, 0, 0, 0, 0};
    if (t < 16) *(short8*)&Xs[(size_t)n * F + t * 8] = z;
    else if (t < 32) *(short8*)&Az[(size_t)n * F + (t - 16) * 8] = z;
  }
}

// ---------------- prepass2: counting-sort scatter -> perm + SORTED ell/cnt/wsum ----------------
// Materializes degree-sorted copies so the conv reads cnt/wsum/ELL coalesced at gid
// (removes 2 random 4B reads + their 128B line pulls + one latency hop per node).
__global__ __launch_bounds__(256) void perm_kernel(
    const int* __restrict__ cnt, const float* __restrict__ wsum,
    const int* __restrict__ hist, int* __restrict__ cursor,
    int* __restrict__ perm, int* __restrict__ cnt_s, float* __restrict__ wsum_s,
    const int* __restrict__ ell, int* __restrict__ ell_s, int n) {
  __shared__ int lh[NBKT], lbase[NBKT];
  int t = threadIdx.x;
  if (t < NBKT) lh[t] = 0;
  __syncthreads();
  int node = blockIdx.x * 256 + t;
  int bkt = 0, idx = 0, cv = 0;
  if (node < n) {
    cv = cnt[node];
    bkt = bucket_of(cv);
    idx = atomicAdd(&lh[bkt], 1);
  }
  __syncthreads();
  if (t < NBKT) {
    int pre = 0;
#pragma unroll
    for (int k = 0; k < NBKT; ++k)
      if (k < t) pre += hist[k];
    lbase[t] = pre + atomicAdd(&cursor[t], lh[t]);
  }
  __syncthreads();
  if (node < n) {
    int dst = lbase[bkt] + idx;
    perm[dst] = node;
    cnt_s[dst] = cv;
    wsum_s[dst] = wsum[node];
    const int4* src = (const int4*)&ell[(size_t)node * ELLCAP];
    int4* d = (int4*)&ell_s[(size_t)dst * ELLCAP];
#pragma unroll
    for (int k = 0; k < 8; ++k) d[k] = src[k];
  }
}

// ---------------- fused conv (R4-proven): degree-uniform gather + MFMA from L2 ----------------
// S = dc*(sum_nbr Xs[r] + Xs[node]); out = relu((S@W^T + wsum*bl)*invdeg + bc)[*dc].
// cnt/wsum/ELL read coalesced at gid (sorted copies); only row reads + output write scatter.
template <bool SCALE_OUT>
__global__ __launch_bounds__(256) void conv_fused(
    const int* __restrict__ cnt_s, const int* __restrict__ ell_s,
    const int* __restrict__ perm,
    const ushort* __restrict__ Xs, const ushort* __restrict__ Wh,
    const float* __restrict__ wsum_s, const float* __restrict__ bl,
    const float* __restrict__ bc, ushort* __restrict__ OUT, int n) {
  const int t = threadIdx.x;
  const int w = t >> 6, lane = t & 63, quad = lane >> 4, cl = lane & 15;
  const int gid = blockIdx.x * 64 + w * 16 + cl;
  const bool valid = gid < n;
  const int sgid = valid ? gid : 0;
  const int node = perm[sgid];

  float acc[4][8];
#pragma unroll
  for (int ks = 0; ks < 4; ++ks)
#pragma unroll
    for (int q = 0; q < 8; ++q) acc[ks][q] = 0.f;

  float dc = 1.f, id = 1.f;
  int nIt = 0;
  if (valid) {
    int cv = cnt_s[sgid];
    float d = (float)(cv + 1);
    dc = rsqrtf(d);
    id = 1.0f / d;
    int lim = cv < ELLCAP ? cv : ELLCAP;
    nIt = (lim + 3) >> 2;
  }
  const int4* ep = (const int4*)&ell_s[(size_t)sgid * ELLCAP];
  const int qoff = quad * 8;

  if (nIt > 0) {
    int4 rr = ep[0];
    for (int it = 0; it < nIt; ++it) {
      const ushort* r0 = &Xs[(size_t)rr.x * F + qoff];
      const ushort* r1 = &Xs[(size_t)rr.y * F + qoff];
      const ushort* r2 = &Xs[(size_t)rr.z * F + qoff];
      const ushort* r3 = &Xs[(size_t)rr.w * F + qoff];
      short8 v[4][4];
#pragma unroll
      for (int ks = 0; ks < 4; ++ks) {
        v[0][ks] = *(const short8*)&r0[ks * 32];
        v[1][ks] = *(const short8*)&r1[ks * 32];
        v[2][ks] = *(const short8*)&r2[ks * 32];
        v[3][ks] = *(const short8*)&r3[ks * 32];
      }
      int jn = (it + 1 < nIt) ? it + 1 : it;
      rr = ep[jn];  // prefetch next indices while rows are in flight
#pragma unroll
      for (int ks = 0; ks < 4; ++ks)
#pragma unroll
        for (int q = 0; q < 8; ++q) {
          float t0 = bf2f((ushort)v[0][ks][q]) + bf2f((ushort)v[1][ks][q]);
          float t1 = bf2f((ushort)v[2][ks][q]) + bf2f((ushort)v[3][ks][q]);
          acc[ks][q] += t0 + t1;
        }
    }
  }

  short8 sfrag[4];
  if (valid) {
    const ushort* sq = &Xs[(size_t)node * F + qoff];
#pragma unroll
    for (int ks = 0; ks < 4; ++ks) {
      short8 sv = *(const short8*)&sq[ks * 32];
      ushort o[8];
#pragma unroll
      for (int q = 0; q < 8; ++q)
        o[q] = f2bf(dc * (acc[ks][q] + bf2f((ushort)sv[q])));
      sfrag[ks] = *(short8*)o;
    }
  } else {
#pragma unroll
    for (int ks = 0; ks < 4; ++ks) sfrag[ks] = (short8){0, 0, 0, 0, 0, 0, 0, 0};
  }

  float4v co[8];
#pragma unroll
  for (int mt = 0; mt < 8; ++mt) co[mt] = (float4v){0.f, 0.f, 0.f, 0.f};
  const int sl = swz(lane);
#pragma unroll
  for (int ks = 0; ks < 4; ++ks) {
    const int base2 = ((ks >> 1) * 1024 + (ks & 1) * 64 + sl) * 8;
#pragma unroll
    for (int mt = 0; mt < 8; ++mt) {
      short8 a_h = *(const short8*)&Wh[base2 + mt * 1024];
      co[mt] = __builtin_amdgcn_mfma_f32_16x16x32_bf16(a_h, sfrag[ks], co[mt], 0, 0, 0);
    }
  }

  if (valid) {
    float ws = wsum_s[sgid];
#pragma unroll
    for (int mt = 0; mt < 8; ++mt) {
      float4 blv = *(const float4*)&bl[mt * 16 + quad * 4];
      float4 bcv = *(const float4*)&bc[mt * 16 + quad * 4];
      float v0 = fmaxf((co[mt][0] + ws * blv.x) * id + bcv.x, 0.f);
      float v1 = fmaxf((co[mt][1] + ws * blv.y) * id + bcv.y, 0.f);
      float v2 = fmaxf((co[mt][2] + ws * blv.z) * id + bcv.z, 0.f);
      float v3 = fmaxf((co[mt][3] + ws * blv.w) * id + bcv.w, 0.f);
      if (SCALE_OUT) { v0 *= dc; v1 *= dc; v2 *= dc; v3 *= dc; }
      ushort o[4] = {f2bf(v0), f2bf(v1), f2bf(v2), f2bf(v3)};
      *(ushort4*)&OUT[(size_t)node * F + mt * 16 + quad * 4] = *(ushort4*)o;
    }
  }
}

// ---------------- fused head (R3-proven): lin1 in LDS exchange, lin2 + log_softmax ----------
__global__ __launch_bounds__(256) void head_fused(const ushort* __restrict__ X,
    const ushort* __restrict__ Wl1h, const float* __restrict__ bl,
    const ushort* __restrict__ W2h, const ushort* __restrict__ W2l,
    const float* __restrict__ b2, float* __restrict__ out, int nrows) {
  __shared__ ushort sH[8192];            // 16 KB h-tile (4 waves x 16 x 128 bf16)
  __shared__ float b2s[48];
  const int t = threadIdx.x;
  if (t < 48) b2s[t] = (t < C_CLS) ? b2[t] : -1e30f;

  const int w = t >> 6, lane = t & 63;
  const int quad = lane >> 4, cl = lane & 15;
  const int sl = swz(lane);
  const int row0 = (blockIdx.x * 4 + w) * 16;
  char* sHb = (char*)sH;

  // ---- phase 1: h[cl][0..127] for this wave's 16 rows ----
  float4v acc1[8];
#pragma unroll
  for (int mt = 0; mt < 8; ++mt) acc1[mt] = (float4v){0.f, 0.f, 0.f, 0.f};
  const int gr1 = row0 + cl;
#pragma unroll
  for (int ks = 0; ks < 4; ++ks) {
    short8 b;
    if (gr1 < nrows) b = *(const short8*)&X[(size_t)gr1 * F + ks * 32 + quad * 8];
    else b = (short8){0, 0, 0, 0, 0, 0, 0, 0};
    const int base = ((ks >> 1) * 1024 + (ks & 1) * 64 + sl) * 8;
#pragma unroll
    for (int mt = 0; mt < 8; ++mt) {
      short8 a_h = *(const short8*)&Wl1h[base + mt * 1024];
      acc1[mt] = __builtin_amdgcn_mfma_f32_16x16x32_bf16(a_h, b, acc1[mt], 0, 0, 0);
    }
  }
#pragma unroll
  for (int mt = 0; mt < 8; ++mt) {
    float4 bv = *(const float4*)&bl[mt * 16 + quad * 4];
    ushort o[4];
    o[0] = f2bf(fmaxf(acc1[mt][0] + bv.x, 0.f));
    o[1] = f2bf(fmaxf(acc1[mt][1] + bv.y, 0.f));
    o[2] = f2bf(fmaxf(acc1[mt][2] + bv.z, 0.f));
    o[3] = f2bf(fmaxf(acc1[mt][3] + bv.w, 0.f));
    int ch = (mt * 2 + (quad >> 1)) ^ cl;
    *(ushort4*)&sHb[w * 4096 + cl * 256 + ch * 16 + (quad & 1) * 8] = *(ushort4*)o;
  }
  __syncthreads();

  // ---- phase 2: logits = h @ W2^T (hi+lo), fused log_softmax ----
  float4v acc[3];
#pragma unroll
  for (int ct = 0; ct < 3; ++ct) acc[ct] = (float4v){0.f, 0.f, 0.f, 0.f};
#pragma unroll
  for (int ks = 0; ks < 4; ++ks) {
    int ch2 = (ks * 4 + quad) ^ cl;
    short8 a = *(short8*)&sHb[w * 4096 + cl * 256 + ch2 * 16];
#pragma unroll
    for (int ct = 0; ct < 3; ++ct) {
      int chunk = ((ct * 4 + ks) * 64 + lane) * 8;
      short8 b_h = *(const short8*)&W2h[chunk];
      short8 b_l = *(const short8*)&W2l[chunk];
      acc[ct] = __builtin_amdgcn_mfma_f32_16x16x32_bf16(a, b_h, acc[ct], 0, 0, 0);
      acc[ct] = __builtin_amdgcn_mfma_f32_16x16x32_bf16(a, b_l, acc[ct], 0, 0, 0);
    }
  }

  float b0 = b2s[cl], b1 = b2s[16 + cl], b2v = b2s[32 + cl];
  float lse[4];
#pragma unroll
  for (int reg = 0; reg < 4; ++reg) {
    float v0 = acc[0][reg] + b0;
    float v1 = acc[1][reg] + b1;
    float v2 = acc[2][reg] + b2v;
    acc[0][reg] = v0; acc[1][reg] = v1; acc[2][reg] = v2;
    float m = fmaxf(fmaxf(v0, v1), v2);
#pragma unroll
    for (int o = 1; o < 16; o <<= 1) m = fmaxf(m, __shfl_xor(m, o));
    float s = __expf(v0 - m) + __expf(v1 - m) + __expf(v2 - m);
#pragma unroll
    for (int o = 1; o < 16; o <<= 1) s += __shfl_xor(s, o);
    lse[reg] = logf(s) + m;
  }
#pragma unroll
  for (int reg = 0; reg < 4; ++reg) {
    int gr = row0 + quad * 4 + reg;
    if (gr < nrows) {
      out[(size_t)gr * C_CLS + cl] = acc[0][reg] - lse[reg];
      out[(size_t)gr * C_CLS + 16 + cl] = acc[1][reg] - lse[reg];
      if (cl < 8) out[(size_t)gr * C_CLS + 32 + cl] = acc[2][reg] - lse[reg];
    }
  }
}

extern "C" void kernel_launch(void* const* d_in, const int* in_sizes, int n_in,
                              void* d_out, int out_size, void* d_ws, size_t ws_size,
                              hipStream_t stream) {
  const float* x    = (const float*)d_in[0];
  const int*   ei   = (const int*)d_in[1];
  const float* imp  = (const float*)d_in[2];
  const float* W1   = (const float*)d_in[3];
  const float* bl1  = (const float*)d_in[4];
  const float* bc1  = (const float*)d_in[5];
  const float* W2   = (const float*)d_in[6];
  const float* bl2  = (const float*)d_in[7];
  const float* bc2  = (const float*)d_in[8];
  const float* W3   = (const float*)d_in[9];
  const float* bl3  = (const float*)d_in[10];
  const float* bc3  = (const float*)d_in[11];
  const float* Wl1  = (const float*)d_in[12];
  const float* bli1 = (const float*)d_in[13];
  const float* Wl2  = (const float*)d_in[14];
  const float* bli2 = (const float*)d_in[15];
  float* out = (float*)d_out;

  const int N = in_sizes[0] / F;      // 100000
  const int E = in_sizes[1] / 2;      // 600000

  // ping-pong buffers have N+1 rows; row N is the shared zero row for ELL tails
  ushort* A16 = (ushort*)d_ws;                     // (N+1)*F
  ushort* B16 = A16 + (size_t)(N + 1) * F;         // (N+1)*F
  ushort* WhP = B16 + (size_t)(N + 1) * F;         // 8192*8
  ushort* W2hH = WhP + 65536;                      // 768*8
  ushort* W2lH = W2hH + 6144;                      // 768*8
  float* wsum = (float*)(W2lH + 6144);             // N
  float* wsum_s = wsum + N;                        // N (sorted)
  int*   cnt  = (int*)(wsum_s + N);                // N (packed)
  int*   hist = cnt + N;                           // 9
  int*   cursor = hist + NBKT;                     // 9
  int*   cnt_s = cursor + NBKT;                    // N (sorted)
  int*   perm = cnt_s + N;                         // N
  int*   ell  = perm + N;                          // 32N
  int*   ell_s = ell + (size_t)32 * N;             // 32N (sorted)

  const int* rowv = ei;
  const int* colv = ei + E;

  int nbE  = (E + 255) / 256;
  int nbW  = (N + 255) / 256;          // prepass wsum/hist blocks
  int nbX  = (N * F + 2047) / 2048;    // prepass x->Xs blocks (8 elems/thread)
  int nbCv = (N + 63) / 64;            // conv blocks (64 nodes each)
  int nbHd = (N + 63) / 64;

  // ---- one-time prep ----
  hipMemsetAsync(cnt, 0, ((size_t)N + 2 * NBKT) * sizeof(int), stream);
  setup_kernel<<<NWSPLIT + nbE, 256, 0, stream>>>(
      W1, imp, W2, W3, Wl1, Wl2, WhP, W2hH, W2lH, rowv, colv, cnt, ell, E, N);
  prepass_kernel<<<nbW + nbX + 1, 256, 0, stream>>>(
      x, cnt, ell, wsum, hist, B16, A16, N, nbW, nbX);
  perm_kernel<<<nbW, 256, 0, stream>>>(cnt, wsum, hist, cursor,
                                       perm, cnt_s, wsum_s, ell, ell_s, N);

  // ---- conv layers: fused gather+GEMM (R4-proven), sorted-coalesced metadata ----
  conv_fused<true ><<<nbCv, 256, 0, stream>>>(cnt_s, ell_s, perm, B16, WhP,         wsum_s, bl1, bc1, A16, N);
  conv_fused<true ><<<nbCv, 256, 0, stream>>>(cnt_s, ell_s, perm, A16, WhP + 16384, wsum_s, bl2, bc2, B16, N);
  conv_fused<false><<<nbCv, 256, 0, stream>>>(cnt_s, ell_s, perm, B16, WhP + 32768, wsum_s, bl3, bc3, A16, N);

  // ---- dense head: lin1 + lin2 + log_softmax (R3-proven) ----
  head_fused<<<nbHd, 256, 0, stream>>>(A16, WhP + 49152, bli1, W2hH, W2lH, bli2, out, N);
}